// Round 1
// baseline (426.538 us; speedup 1.0000x reference)
//
#include <hip/hip_runtime.h>
#include <cstdint>

typedef unsigned short u16;
typedef __bf16 bf16x8 __attribute__((ext_vector_type(8)));
typedef float f32x4 __attribute__((ext_vector_type(4)));

__device__ __forceinline__ u16 f2bf(float f) {
  union { float f; uint32_t u; } v; v.f = f;
  uint32_t r = v.u + 0x7fffu + ((v.u >> 16) & 1u);
  return (u16)(r >> 16);
}
__device__ __forceinline__ float bf2f(u16 u) {
  union { uint32_t u; float f; } v; v.u = ((uint32_t)u) << 16;
  return v.f;
}

// async global->LDS, 16B per lane. LDS dest is wave-uniform base + lane*16.
__device__ __forceinline__ void gload16(const void* g, const void* l) {
  __builtin_amdgcn_global_load_lds(
      (const __attribute__((address_space(1))) uint32_t*)(uintptr_t)g,
      (__attribute__((address_space(3))) uint32_t*)(uintptr_t)l, 16, 0, 0);
}

__device__ __forceinline__ f32x4 mfma16(bf16x8 a, bf16x8 b, f32x4 c) {
  return __builtin_amdgcn_mfma_f32_16x16x32_bf16(a, b, c, 0, 0, 0);
}

// ---------------- convert fp32 -> bf16 (vectorized) ----------------
__global__ __launch_bounds__(256)
void k_cvt(const float* __restrict__ src, u16* __restrict__ dst, int n4) {
  int i = blockIdx.x * 256 + threadIdx.x;
  if (i >= n4) return;
  float4 v = ((const float4*)src)[i];
  union { u16 s[4]; uint2 u; } o;
  o.s[0] = f2bf(v.x); o.s[1] = f2bf(v.y); o.s[2] = f2bf(v.z); o.s[3] = f2bf(v.w);
  ((uint2*)dst)[i] = o.u;
}

// ------------- transpose fp32 [R][C] -> bf16 [C][R] (64x64 tiles) -------------
__global__ __launch_bounds__(256)
void k_transpose(const float* __restrict__ src, u16* __restrict__ dst, int R, int Cc) {
  __shared__ u16 t[64 * 66];
  int r0 = blockIdx.y * 64, c0 = blockIdx.x * 64;
  #pragma unroll
  for (int i = 0; i < 16; i++) {
    int e = i * 256 + threadIdx.x;
    int rl = e >> 6, cl = e & 63;
    t[cl * 66 + rl] = f2bf(src[(size_t)(r0 + rl) * Cc + c0 + cl]);
  }
  __syncthreads();
  #pragma unroll
  for (int i = 0; i < 16; i++) {
    int e = i * 256 + threadIdx.x;
    int ro = e >> 6, co = e & 63;
    dst[(size_t)(c0 + ro) * R + r0 + co] = t[ro * 66 + co];
  }
}

// ---------------- tcomb[b][j] = temb[b]@Wt[:,j] + bt[j] + bqkv[j] ----------------
__global__ __launch_bounds__(256)
void k_temb(const float* __restrict__ temb, const float* __restrict__ Wt,
            const float* __restrict__ bt, const float* __restrict__ bqkv,
            float* __restrict__ tcomb) {
  int j = blockIdx.x * 256 + threadIdx.x;   // 0..3071
  int b = blockIdx.y;
  float acc = 0.f;
  for (int k = 0; k < 1024; k++)
    acc += temb[b * 1024 + k] * Wt[(size_t)k * 3072 + j];
  tcomb[b * 3072 + j] = acc + bt[j] + bqkv[j];
}

// ---------------- bf16 MFMA GEMM: C[M][Ntot] = A[M][K] @ Bt[N][K]^T ----------------
// MODE 0: out bf16, bias = tcomb[b][col] (row-dependent). MODE 1: out fp32, bias = bp[col].
template <int MODE>
__global__ __launch_bounds__(256, 2)
void k_gemm(const u16* __restrict__ A, const u16* __restrict__ Bt,
            u16* __restrict__ outb, float* __restrict__ outf,
            const float* __restrict__ bias, int K, int Ntot) {
  __shared__ u16 As[128 * 32];
  __shared__ u16 Bs[128 * 32];
  const int m0 = blockIdx.y * 128;
  const int n0 = blockIdx.x * 128;
  const int lane = threadIdx.x & 63;
  const int w = threadIdx.x >> 6;
  const int wm = (w & 1) * 64;
  const int wn = (w >> 1) * 64;

  f32x4 acc[4][4];
  #pragma unroll
  for (int i = 0; i < 4; i++)
    #pragma unroll
    for (int j = 0; j < 4; j++) acc[i][j] = (f32x4){0.f, 0.f, 0.f, 0.f};

  const int rA = lane >> 2;          // 0..15 row within 16-row stripe
  const int cA = (lane & 3) * 8;     // 16B chunk within 64B row
  const u16* Ag = A + (size_t)(m0 + rA) * K + cA;
  const u16* Bg = Bt + (size_t)(n0 + rA) * K + cA;

  for (int k0 = 0; k0 < K; k0 += 32) {
    #pragma unroll
    for (int tt = 0; tt < 2; tt++) {
      int t = 2 * w + tt;
      gload16(Ag + (size_t)(16 * t) * K + k0, &As[t * 512]);
      gload16(Bg + (size_t)(16 * t) * K + k0, &Bs[t * 512]);
    }
    __syncthreads();
    bf16x8 af[4], bfr[4];
    #pragma unroll
    for (int i = 0; i < 4; i++)
      af[i] = *(const bf16x8*)&As[(wm + 16 * i + (lane & 15)) * 32 + (lane >> 4) * 8];
    #pragma unroll
    for (int j = 0; j < 4; j++)
      bfr[j] = *(const bf16x8*)&Bs[(wn + 16 * j + (lane & 15)) * 32 + (lane >> 4) * 8];
    #pragma unroll
    for (int i = 0; i < 4; i++)
      #pragma unroll
      for (int j = 0; j < 4; j++)
        acc[i][j] = mfma16(af[i], bfr[j], acc[i][j]);
    __syncthreads();
  }

  const int rl = (lane >> 4) * 4;
  const int cl = lane & 15;
  #pragma unroll
  for (int i = 0; i < 4; i++) {
    #pragma unroll
    for (int j = 0; j < 4; j++) {
      #pragma unroll
      for (int r = 0; r < 4; r++) {
        int grow = m0 + wm + 16 * i + rl + r;
        int gcol = n0 + wn + 16 * j + cl;
        float v = acc[i][j][r];
        if (MODE == 0) {
          int b = grow >> 10;
          v += bias[b * Ntot + gcol];
          outb[(size_t)grow * Ntot + gcol] = f2bf(v);
        } else {
          v += bias[gcol];
          outf[(size_t)grow * Ntot + gcol] = v;
        }
      }
    }
  }
}

// ---------------- per-head RMSNorm + axial RoPE on q,k ----------------
__global__ __launch_bounds__(256)
void k_rmsrope(const u16* __restrict__ qkv,
               const float* __restrict__ cos_y, const float* __restrict__ sin_y,
               const float* __restrict__ cos_x, const float* __restrict__ sin_x,
               const float* __restrict__ qn_w, const float* __restrict__ kn_w,
               u16* __restrict__ Qo, u16* __restrict__ Ko) {
  int wid = blockIdx.x * 4 + (threadIdx.x >> 6);  // (b*1024+n)*16 + h
  int lane = threadIdx.x & 63;
  int h = wid & 15;
  int bn = wid >> 4;          // b*1024+n
  int n = bn & 1023;
  int b = bn >> 10;
  size_t base = (size_t)bn * 3072 + h * 64 + lane;
  float qv = bf2f(qkv[base]);
  float kv = bf2f(qkv[base + 1024]);
  float sq = qv * qv, sk = kv * kv;
  #pragma unroll
  for (int mask = 1; mask < 64; mask <<= 1) {
    sq += __shfl_xor(sq, mask);
    sk += __shfl_xor(sk, mask);
  }
  float rq = rsqrtf(sq * (1.0f / 64.0f) + 1e-6f);
  float rk = rsqrtf(sk * (1.0f / 64.0f) + 1e-6f);
  float qn = qv * rq * qn_w[lane];
  float kn = kv * rk * kn_w[lane];
  float qp = __shfl_xor(qn, 16);
  float kp = __shfl_xor(kn, 16);
  float sgn = (lane & 16) ? 1.0f : -1.0f;
  float c, s;
  if (lane < 32) { c = cos_y[n * 32 + lane];      s = sin_y[n * 32 + lane]; }
  else           { c = cos_x[n * 32 + lane - 32]; s = sin_x[n * 32 + lane - 32]; }
  float qo = qn * c + sgn * qp * s;
  float ko = kn * c + sgn * kp * s;
  size_t obase = ((size_t)(b * 16 + h) * 1024 + n) * 64 + lane;
  Qo[obase] = f2bf(qo);
  Ko[obase] = f2bf(ko);
}

// ---------------- V relayout: qkv v-slice [b,n,h,d] -> VT [b,h,d,n] ----------------
__global__ __launch_bounds__(256)
void k_vtrans(const u16* __restrict__ qkv, u16* __restrict__ VT) {
  __shared__ u16 t[64 * 66];
  int n0 = blockIdx.x * 64;
  int h = blockIdx.y, b = blockIdx.z;
  #pragma unroll
  for (int i = 0; i < 16; i++) {
    int e = i * 256 + threadIdx.x;
    int nl = e >> 6, d = e & 63;
    t[d * 66 + nl] = qkv[(size_t)(b * 1024 + n0 + nl) * 3072 + 2048 + h * 64 + d];
  }
  __syncthreads();
  #pragma unroll
  for (int i = 0; i < 16; i++) {
    int e = i * 256 + threadIdx.x;
    int d = e >> 6, nl = e & 63;
    VT[((size_t)(b * 16 + h) * 64 + d) * 1024 + n0 + nl] = t[d * 66 + nl];
  }
}

// ---------------- flash attention ----------------
// swizzled LDS offset for logical (row, col) in a [64][64] bf16 tile:
// 16B chunks XORed by row&7 -> conflict-free b128 column reads.
__device__ __forceinline__ int swz(int row, int col) {
  return row * 64 + ((((col >> 3) ^ (row & 7)) << 3) | (col & 7));
}

__global__ __launch_bounds__(256, 2)
void k_attn(const u16* __restrict__ Q, const u16* __restrict__ Kb,
            const u16* __restrict__ VT, u16* __restrict__ Ob) {
  __shared__ u16 Qs[64 * 64], Ks[64 * 64], VTs[64 * 64], Ps[64 * 64];
  const int lane = threadIdx.x & 63;
  const int w = threadIdx.x >> 6;
  const int qt = blockIdx.x, h = blockIdx.y, b = blockIdx.z;
  const int bh = b * 16 + h;
  const size_t base = (size_t)bh * 1024 * 64;   // same stride for Q,K (N*64) and VT (64*N)
  const int q0 = qt * 64;
  // staging source column chunk (XOR swizzle vs row&7); row within instr = lane>>3
  const int scol = (((lane & 7) ^ (lane >> 3)) * 8);

  #pragma unroll
  for (int tt = 0; tt < 2; tt++) {
    int t = 2 * w + tt;
    gload16(Q + base + (size_t)(q0 + 8 * t + (lane >> 3)) * 64 + scol, &Qs[t * 512]);
  }

  f32x4 acc_o[4];
  #pragma unroll
  for (int dt = 0; dt < 4; dt++) acc_o[dt] = (f32x4){0.f, 0.f, 0.f, 0.f};
  float mrow[4], lrow[4];
  #pragma unroll
  for (int r = 0; r < 4; r++) { mrow[r] = -__builtin_inff(); lrow[r] = 0.f; }

  for (int j0 = 0; j0 < 1024; j0 += 64) {
    __syncthreads();  // prev iter's reads of Ks/VTs done
    #pragma unroll
    for (int tt = 0; tt < 2; tt++) {
      int t = 2 * w + tt;
      gload16(Kb + base + (size_t)(j0 + 8 * t + (lane >> 3)) * 64 + scol, &Ks[t * 512]);
      gload16(VT + base + (size_t)(8 * t + (lane >> 3)) * 1024 + j0 + scol, &VTs[t * 512]);
    }
    __syncthreads();  // staging (and Q on first iter) complete

    // S = Q K^T for this wave's 16 q-rows x 64 keys
    f32x4 accs[4];
    #pragma unroll
    for (int nt = 0; nt < 4; nt++) accs[nt] = (f32x4){0.f, 0.f, 0.f, 0.f};
    #pragma unroll
    for (int s = 0; s < 2; s++) {
      bf16x8 aq = *(const bf16x8*)&Qs[swz(w * 16 + (lane & 15), s * 32 + (lane >> 4) * 8)];
      #pragma unroll
      for (int nt = 0; nt < 4; nt++) {
        bf16x8 bk = *(const bf16x8*)&Ks[swz(nt * 16 + (lane & 15), s * 32 + (lane >> 4) * 8)];
        accs[nt] = mfma16(aq, bk, accs[nt]);
      }
    }
    #pragma unroll
    for (int nt = 0; nt < 4; nt++)
      #pragma unroll
      for (int r = 0; r < 4; r++) accs[nt][r] *= 0.125f;  // 1/sqrt(64)

    // online softmax (row stats live in the 16-lane group owning the row)
    float mnew[4], alpha[4];
    #pragma unroll
    for (int r = 0; r < 4; r++) {
      float mx = fmaxf(fmaxf(accs[0][r], accs[1][r]), fmaxf(accs[2][r], accs[3][r]));
      #pragma unroll
      for (int mask = 1; mask < 16; mask <<= 1) mx = fmaxf(mx, __shfl_xor(mx, mask));
      mnew[r] = fmaxf(mrow[r], mx);
      alpha[r] = __expf(mrow[r] - mnew[r]);
      mrow[r] = mnew[r];
    }
    float rsum[4] = {0.f, 0.f, 0.f, 0.f};
    #pragma unroll
    for (int nt = 0; nt < 4; nt++)
      #pragma unroll
      for (int r = 0; r < 4; r++) {
        float p = __expf(accs[nt][r] - mnew[r]);
        accs[nt][r] = p;
        rsum[r] += p;
      }
    #pragma unroll
    for (int r = 0; r < 4; r++) {
      #pragma unroll
      for (int mask = 1; mask < 16; mask <<= 1) rsum[r] += __shfl_xor(rsum[r], mask);
      lrow[r] = lrow[r] * alpha[r] + rsum[r];
      #pragma unroll
      for (int dt = 0; dt < 4; dt++) acc_o[dt][r] *= alpha[r];
    }

    // P -> LDS (own wave strip only), then PV
    #pragma unroll
    for (int nt = 0; nt < 4; nt++)
      #pragma unroll
      for (int r = 0; r < 4; r++)
        Ps[swz(w * 16 + (lane >> 4) * 4 + r, nt * 16 + (lane & 15))] = f2bf(accs[nt][r]);
    __syncthreads();  // make P visible across lanes (full barrier: safe round-1 choice)
    #pragma unroll
    for (int s = 0; s < 2; s++) {
      bf16x8 ap = *(const bf16x8*)&Ps[swz(w * 16 + (lane & 15), s * 32 + (lane >> 4) * 8)];
      #pragma unroll
      for (int dt = 0; dt < 4; dt++) {
        bf16x8 bv = *(const bf16x8*)&VTs[swz(dt * 16 + (lane & 15), s * 32 + (lane >> 4) * 8)];
        acc_o[dt] = mfma16(ap, bv, acc_o[dt]);
      }
    }
  }

  // epilogue: O / l, write att [b, n, h*64+d] bf16
  #pragma unroll
  for (int dt = 0; dt < 4; dt++)
    #pragma unroll
    for (int r = 0; r < 4; r++) {
      int row = q0 + w * 16 + (lane >> 4) * 4 + r;
      int col = h * 64 + dt * 16 + (lane & 15);
      float ov = acc_o[dt][r] / lrow[r];
      Ob[((size_t)b * 1024 + row) * 1024 + col] = f2bf(ov);
    }
}

// ---------------- launch ----------------
extern "C" void kernel_launch(void* const* d_in, const int* in_sizes, int n_in,
                              void* d_out, int out_size, void* d_ws, size_t ws_size,
                              hipStream_t stream) {
  const float* x     = (const float*)d_in[0];
  const float* temb  = (const float*)d_in[1];
  const float* cos_y = (const float*)d_in[2];
  const float* sin_y = (const float*)d_in[3];
  const float* cos_x = (const float*)d_in[4];
  const float* sin_x = (const float*)d_in[5];
  const float* Wqkv  = (const float*)d_in[6];
  const float* bqkv  = (const float*)d_in[7];
  const float* Wt    = (const float*)d_in[8];
  const float* bt    = (const float*)d_in[9];
  const float* Wp    = (const float*)d_in[10];
  const float* bp    = (const float*)d_in[11];
  const float* qn_w  = (const float*)d_in[12];
  const float* kn_w  = (const float*)d_in[13];
  float* out = (float*)d_out;

  char* ws = (char*)d_ws;
  u16*   x_bf  = (u16*)(ws);                  // 16 MB; reused as att after QKV GEMM
  u16*   WqkvT = (u16*)(ws + 16777216);       // 6 MB
  u16*   WpT   = (u16*)(ws + 23068672);       // 2 MB
  float* tcomb = (float*)(ws + 25165824);     // 96 KB
  u16*   qkv   = (u16*)(ws + 25264128);       // 48 MB
  u16*   Qb    = (u16*)(ws + 75595776);       // 16 MB
  u16*   Kb    = (u16*)(ws + 92372992);       // 16 MB
  u16*   VTb   = (u16*)(ws + 109150208);      // 16 MB
  u16*   att   = x_bf;

  k_cvt<<<8192, 256, 0, stream>>>(x, x_bf, 8192 * 1024 / 4);
  k_transpose<<<dim3(48, 16), 256, 0, stream>>>(Wqkv, WqkvT, 1024, 3072);
  k_transpose<<<dim3(16, 16), 256, 0, stream>>>(Wp, WpT, 1024, 1024);
  k_temb<<<dim3(12, 8), 256, 0, stream>>>(temb, Wt, bt, bqkv, tcomb);
  k_gemm<0><<<dim3(24, 64), 256, 0, stream>>>(x_bf, WqkvT, qkv, nullptr, tcomb, 1024, 3072);
  k_rmsrope<<<32768, 256, 0, stream>>>(qkv, cos_y, sin_y, cos_x, sin_x, qn_w, kn_w, Qb, Kb);
  k_vtrans<<<dim3(16, 16, 8), 256, 0, stream>>>(qkv, VTb);
  k_attn<<<dim3(16, 16, 8), 256, 0, stream>>>(Qb, Kb, VTb, att);
  k_gemm<1><<<dim3(8, 64), 256, 0, stream>>>(att, WpT, nullptr, out, bp, 1024, 1024);
}

// Round 3
// 409.797 us; speedup vs baseline: 1.0409x; 1.0409x over previous
//
#include <hip/hip_runtime.h>
#include <cstdint>

typedef unsigned short u16;
typedef __bf16 bf16x8 __attribute__((ext_vector_type(8)));
typedef float f32x4 __attribute__((ext_vector_type(4)));

__device__ __forceinline__ u16 f2bf(float f) {
  __bf16 h = (__bf16)f;               // HW v_cvt (RNE) on gfx950
  return __builtin_bit_cast(u16, h);
}
__device__ __forceinline__ float bf2f(u16 u) {
  union { uint32_t u; float f; } v; v.u = ((uint32_t)u) << 16;
  return v.f;
}

// async global->LDS, 16B per lane. LDS dest is wave-uniform base + lane*16.
__device__ __forceinline__ void gload16(const void* g, const void* l) {
  __builtin_amdgcn_global_load_lds(
      (const __attribute__((address_space(1))) uint32_t*)(uintptr_t)g,
      (__attribute__((address_space(3))) uint32_t*)(uintptr_t)l, 16, 0, 0);
}

__device__ __forceinline__ f32x4 mfma16(bf16x8 a, bf16x8 b, f32x4 c) {
  return __builtin_amdgcn_mfma_f32_16x16x32_bf16(a, b, c, 0, 0, 0);
}

// swizzled LDS offset for logical (row, col) in a [*][64] bf16 tile:
// 16B chunks XORed by row&7 -> conflict-free b128 reads (verified: 0 conflicts R1).
__device__ __forceinline__ int swz(int row, int col) {
  return row * 64 + ((((col >> 3) ^ (row & 7)) << 3) | (col & 7));
}

// ---------------- convert fp32 -> bf16 (vectorized) ----------------
__global__ __launch_bounds__(256)
void k_cvt(const float* __restrict__ src, u16* __restrict__ dst, int n4) {
  int i = blockIdx.x * 256 + threadIdx.x;
  if (i >= n4) return;
  float4 v = ((const float4*)src)[i];
  union { u16 s[4]; uint2 u; } o;
  o.s[0] = f2bf(v.x); o.s[1] = f2bf(v.y); o.s[2] = f2bf(v.z); o.s[3] = f2bf(v.w);
  ((uint2*)dst)[i] = o.u;
}

// ------------- transpose fp32 [R][C] -> bf16 [C][R] (64x64 tiles) -------------
__global__ __launch_bounds__(256)
void k_transpose(const float* __restrict__ src, u16* __restrict__ dst, int R, int Cc) {
  __shared__ u16 t[64 * 66];
  int r0 = blockIdx.y * 64, c0 = blockIdx.x * 64;
  #pragma unroll
  for (int i = 0; i < 16; i++) {
    int e = i * 256 + threadIdx.x;
    int rl = e >> 6, cl = e & 63;
    t[cl * 66 + rl] = f2bf(src[(size_t)(r0 + rl) * Cc + c0 + cl]);
  }
  __syncthreads();
  #pragma unroll
  for (int i = 0; i < 16; i++) {
    int e = i * 256 + threadIdx.x;
    int ro = e >> 6, co = e & 63;
    dst[(size_t)(c0 + ro) * R + r0 + co] = t[ro * 66 + co];
  }
}

// ---------------- tcomb[b][j] = temb[b]@Wt[:,j] + bt[j] + bqkv[j] ----------------
__global__ __launch_bounds__(256)
void k_temb(const float* __restrict__ temb, const float* __restrict__ Wt,
            const float* __restrict__ bt, const float* __restrict__ bqkv,
            float* __restrict__ tcomb) {
  int j = blockIdx.x * 256 + threadIdx.x;   // 0..3071
  int b = blockIdx.y;
  const float* tb = temb + b * 1024;
  float a0 = 0.f, a1 = 0.f, a2 = 0.f, a3 = 0.f;
  for (int k = 0; k < 1024; k += 4) {
    a0 += tb[k]     * Wt[(size_t)k * 3072 + j];
    a1 += tb[k + 1] * Wt[(size_t)(k + 1) * 3072 + j];
    a2 += tb[k + 2] * Wt[(size_t)(k + 2) * 3072 + j];
    a3 += tb[k + 3] * Wt[(size_t)(k + 3) * 3072 + j];
  }
  tcomb[b * 3072 + j] = (a0 + a1) + (a2 + a3) + bt[j] + bqkv[j];
}

// ---------------- bf16 MFMA GEMM: C[M][Ntot] = A[M][K] @ Bt[N][K]^T ----------------
template <int MODE>
__global__ __launch_bounds__(256, 2)
void k_gemm(const u16* __restrict__ A, const u16* __restrict__ Bt,
            u16* __restrict__ outb, float* __restrict__ outf,
            const float* __restrict__ bias, int K, int Ntot) {
  __shared__ u16 As[128 * 32];
  __shared__ u16 Bs[128 * 32];
  const int m0 = blockIdx.y * 128;
  const int n0 = blockIdx.x * 128;
  const int lane = threadIdx.x & 63;
  const int w = threadIdx.x >> 6;
  const int wm = (w & 1) * 64;
  const int wn = (w >> 1) * 64;

  f32x4 acc[4][4];
  #pragma unroll
  for (int i = 0; i < 4; i++)
    #pragma unroll
    for (int j = 0; j < 4; j++) acc[i][j] = (f32x4){0.f, 0.f, 0.f, 0.f};

  const int rA = lane >> 2;
  const int cA = (lane & 3) * 8;
  const u16* Ag = A + (size_t)(m0 + rA) * K + cA;
  const u16* Bg = Bt + (size_t)(n0 + rA) * K + cA;

  for (int k0 = 0; k0 < K; k0 += 32) {
    #pragma unroll
    for (int tt = 0; tt < 2; tt++) {
      int t = 2 * w + tt;
      gload16(Ag + (size_t)(16 * t) * K + k0, &As[t * 512]);
      gload16(Bg + (size_t)(16 * t) * K + k0, &Bs[t * 512]);
    }
    __syncthreads();
    bf16x8 af[4], bfr[4];
    #pragma unroll
    for (int i = 0; i < 4; i++)
      af[i] = *(const bf16x8*)&As[(wm + 16 * i + (lane & 15)) * 32 + (lane >> 4) * 8];
    #pragma unroll
    for (int j = 0; j < 4; j++)
      bfr[j] = *(const bf16x8*)&Bs[(wn + 16 * j + (lane & 15)) * 32 + (lane >> 4) * 8];
    #pragma unroll
    for (int i = 0; i < 4; i++)
      #pragma unroll
      for (int j = 0; j < 4; j++)
        acc[i][j] = mfma16(af[i], bfr[j], acc[i][j]);
    __syncthreads();
  }

  const int rl = (lane >> 4) * 4;
  const int cl = lane & 15;
  #pragma unroll
  for (int i = 0; i < 4; i++) {
    #pragma unroll
    for (int j = 0; j < 4; j++) {
      #pragma unroll
      for (int r = 0; r < 4; r++) {
        int grow = m0 + wm + 16 * i + rl + r;
        int gcol = n0 + wn + 16 * j + cl;
        float v = acc[i][j][r];
        if (MODE == 0) {
          int b = grow >> 10;
          v += bias[b * Ntot + gcol];
          outb[(size_t)grow * Ntot + gcol] = f2bf(v);
        } else {
          v += bias[gcol];
          outf[(size_t)grow * Ntot + gcol] = v;
        }
      }
    }
  }
}

// ------- fused per-head RMSNorm + axial RoPE (q,k) + V transpose -------
// Q output pre-scaled by 1/sqrt(64) so attention skips the score scale.
__global__ __launch_bounds__(256)
void k_rrv(const u16* __restrict__ qkv,
           const float* __restrict__ cos_y, const float* __restrict__ sin_y,
           const float* __restrict__ cos_x, const float* __restrict__ sin_x,
           const float* __restrict__ qn_w, const float* __restrict__ kn_w,
           u16* __restrict__ Qo, u16* __restrict__ Ko, u16* __restrict__ VT) {
  __shared__ u16 t[64 * 68];
  const int n0 = blockIdx.x * 64, h = blockIdx.y, b = blockIdx.z;
  const int bh = b * 16 + h;
  const int lane = threadIdx.x & 63, w = threadIdx.x >> 6;
  const int l15 = lane & 15, lg = lane >> 4;
  float4 qw = *(const float4*)(qn_w + l15 * 4);
  float4 kw = *(const float4*)(kn_w + l15 * 4);
  const float sgn = (lane & 4) ? 1.0f : -1.0f;   // rotate partner is d^16 within each 32-half
  const float* ct = (lane & 8) ? cos_x : cos_y;
  const float* st = (lane & 8) ? sin_x : sin_y;

  #pragma unroll
  for (int rr = 0; rr < 4; rr++) {
    int row = n0 + w * 16 + rr * 4 + lg;
    size_t src = (size_t)(b * 1024 + row) * 3072 + h * 64 + l15 * 4;
    uint2 qu = *(const uint2*)(qkv + src);
    uint2 ku = *(const uint2*)(qkv + src + 1024);
    float q[4], k[4];
    q[0] = bf2f((u16)qu.x); q[1] = bf2f((u16)(qu.x >> 16));
    q[2] = bf2f((u16)qu.y); q[3] = bf2f((u16)(qu.y >> 16));
    k[0] = bf2f((u16)ku.x); k[1] = bf2f((u16)(ku.x >> 16));
    k[2] = bf2f((u16)ku.y); k[3] = bf2f((u16)(ku.y >> 16));
    float sq = q[0]*q[0] + q[1]*q[1] + q[2]*q[2] + q[3]*q[3];
    float sk = k[0]*k[0] + k[1]*k[1] + k[2]*k[2] + k[3]*k[3];
    #pragma unroll
    for (int m = 1; m < 16; m <<= 1) {
      sq += __shfl_xor(sq, m);
      sk += __shfl_xor(sk, m);
    }
    float rq = rsqrtf(sq * (1.0f / 64.0f) + 1e-6f);
    float rk = rsqrtf(sk * (1.0f / 64.0f) + 1e-6f);
    float4 cc = *(const float4*)(ct + (size_t)row * 32 + (lane & 7) * 4);
    float4 ss = *(const float4*)(st + (size_t)row * 32 + (lane & 7) * 4);
    float qn[4], kn[4];
    qn[0] = q[0]*rq*qw.x; qn[1] = q[1]*rq*qw.y; qn[2] = q[2]*rq*qw.z; qn[3] = q[3]*rq*qw.w;
    kn[0] = k[0]*rk*kw.x; kn[1] = k[1]*rk*kw.y; kn[2] = k[2]*rk*kw.z; kn[3] = k[3]*rk*kw.w;
    float c[4] = {cc.x, cc.y, cc.z, cc.w};
    float s[4] = {ss.x, ss.y, ss.z, ss.w};
    union { u16 e[4]; uint2 u; } oq, ok;
    #pragma unroll
    for (int j = 0; j < 4; j++) {
      float qp = __shfl_xor(qn[j], 4);   // partner chunk (l15^4) == d^16
      float kp = __shfl_xor(kn[j], 4);
      oq.e[j] = f2bf((qn[j] * c[j] + sgn * qp * s[j]) * 0.125f);
      ok.e[j] = f2bf(kn[j] * c[j] + sgn * kp * s[j]);
    }
    size_t dst = ((size_t)bh * 1024 + row) * 64 + l15 * 4;
    *(uint2*)(Qo + dst) = oq.u;
    *(uint2*)(Ko + dst) = ok.u;
  }

  // V transpose: qkv v-slice [n][d] -> VT [bh][d][n]
  #pragma unroll
  for (int i = 0; i < 4; i++) {
    int e = i * 256 + threadIdx.x;
    int n = e >> 4, dc = e & 15;
    uint2 v = *(const uint2*)(qkv + (size_t)(b * 1024 + n0 + n) * 3072 + 2048 + h * 64 + dc * 4);
    t[(dc * 4 + 0) * 68 + n] = (u16)v.x;
    t[(dc * 4 + 1) * 68 + n] = (u16)(v.x >> 16);
    t[(dc * 4 + 2) * 68 + n] = (u16)v.y;
    t[(dc * 4 + 3) * 68 + n] = (u16)(v.y >> 16);
  }
  __syncthreads();
  #pragma unroll
  for (int i = 0; i < 4; i++) {
    int e = i * 256 + threadIdx.x;
    int d = e >> 4, nc = e & 15;
    const u16* p = &t[d * 68 + nc * 4];
    uint2 o;
    o.x = (uint32_t)p[0] | ((uint32_t)p[1] << 16);
    o.y = (uint32_t)p[2] | ((uint32_t)p[3] << 16);
    *(uint2*)(VT + ((size_t)bh * 64 + d) * 1024 + n0 + nc * 4) = o;
  }
}

// ---------------- flash attention, 128 q-rows/block, dbuf K/V, 1 barrier/iter ----------------
__global__ __launch_bounds__(256, 2)
void k_attn(const u16* __restrict__ Q, const u16* __restrict__ Kb,
            const u16* __restrict__ VT, u16* __restrict__ Ob) {
  __shared__ u16 Ks[2][4096], VTs[2][4096], Ps[4][2048];
  const int lane = threadIdx.x & 63;
  const int w = threadIdx.x >> 6;
  const int bh = blockIdx.x;          // b*16+h : all 8 q-tiles of a bh land on one XCD
  const int qt = blockIdx.y;
  const int b = bh >> 4, h = bh & 15;
  const size_t base = (size_t)bh * 65536;
  const int q0 = qt * 128;
  const int scol = ((lane & 7) ^ (lane >> 3)) * 8;  // XOR-swizzled source chunk for staging
  const int lr = lane >> 3;

  // Q fragments in registers (pre-scaled by 1/8 in k_rrv)
  bf16x8 aq[2][2];
  #pragma unroll
  for (int i = 0; i < 2; i++)
    #pragma unroll
    for (int s = 0; s < 2; s++)
      aq[i][s] = *(const bf16x8*)(Q + base +
          (size_t)(q0 + w * 32 + i * 16 + (lane & 15)) * 64 + s * 32 + (lane >> 4) * 8);

  f32x4 acc_o[2][4];
  float mrow[2][4], lrow[2][4];
  #pragma unroll
  for (int i = 0; i < 2; i++)
    #pragma unroll
    for (int r = 0; r < 4; r++) {
      acc_o[i][r] = (f32x4){0.f, 0.f, 0.f, 0.f};
      mrow[i][r] = -__builtin_inff();
      lrow[i][r] = 0.f;
    }

  // stage j-tile 0 into buf 0
  #pragma unroll
  for (int tt = 0; tt < 2; tt++) {
    int t = w * 2 + tt;
    gload16(Kb + base + (size_t)(8 * t + lr) * 64 + scol, &Ks[0][t * 512]);
    gload16(VT + base + (size_t)(8 * t + lr) * 1024 + scol, &VTs[0][t * 512]);
  }

  for (int it = 0; it < 16; it++) {
    __syncthreads();                 // staging of cur complete; all readers of nxt (prev iter) done
    const int cur = it & 1;
    if (it < 15) {                   // prefetch next tile; latency hidden behind this iter's compute
      const int nxt = cur ^ 1;
      const int j1 = (it + 1) * 64;
      #pragma unroll
      for (int tt = 0; tt < 2; tt++) {
        int t = w * 2 + tt;
        gload16(Kb + base + (size_t)(j1 + 8 * t + lr) * 64 + scol, &Ks[nxt][t * 512]);
        gload16(VT + base + (size_t)(8 * t + lr) * 1024 + j1 + scol, &VTs[nxt][t * 512]);
      }
    }
    const u16* K_ = Ks[cur];
    const u16* V_ = VTs[cur];

    // S = Q K^T : 2 strips x 64 keys
    f32x4 accs[2][4];
    #pragma unroll
    for (int i = 0; i < 2; i++)
      #pragma unroll
      for (int nt = 0; nt < 4; nt++) accs[i][nt] = (f32x4){0.f, 0.f, 0.f, 0.f};
    #pragma unroll
    for (int s = 0; s < 2; s++) {
      bf16x8 bk[4];
      #pragma unroll
      for (int nt = 0; nt < 4; nt++)
        bk[nt] = *(const bf16x8*)&K_[swz(nt * 16 + (lane & 15), s * 32 + (lane >> 4) * 8)];
      #pragma unroll
      for (int i = 0; i < 2; i++)
        #pragma unroll
        for (int nt = 0; nt < 4; nt++)
          accs[i][nt] = mfma16(aq[i][s], bk[nt], accs[i][nt]);
    }

    // online softmax + P into wave-private LDS strip (no barrier needed)
    #pragma unroll
    for (int i = 0; i < 2; i++) {
      float al[4];
      #pragma unroll
      for (int r = 0; r < 4; r++) {
        float mx = fmaxf(fmaxf(accs[i][0][r], accs[i][1][r]),
                         fmaxf(accs[i][2][r], accs[i][3][r]));
        #pragma unroll
        for (int m = 1; m < 16; m <<= 1) mx = fmaxf(mx, __shfl_xor(mx, m));
        float mn = fmaxf(mrow[i][r], mx);
        al[r] = __expf(mrow[i][r] - mn);
        mrow[i][r] = mn;
      }
      float rs[4] = {0.f, 0.f, 0.f, 0.f};
      #pragma unroll
      for (int nt = 0; nt < 4; nt++)
        #pragma unroll
        for (int r = 0; r < 4; r++) {
          float p = __expf(accs[i][nt][r] - mrow[i][r]);
          accs[i][nt][r] = p;
          rs[r] += p;
        }
      #pragma unroll
      for (int r = 0; r < 4; r++) {
        #pragma unroll
        for (int m = 1; m < 16; m <<= 1) rs[r] += __shfl_xor(rs[r], m);
        lrow[i][r] = lrow[i][r] * al[r] + rs[r];
        #pragma unroll
        for (int dt = 0; dt < 4; dt++) acc_o[i][dt][r] *= al[r];
      }
      #pragma unroll
      for (int nt = 0; nt < 4; nt++)
        #pragma unroll
        for (int r = 0; r < 4; r++)
          Ps[w][swz(i * 16 + (lane >> 4) * 4 + r, nt * 16 + (lane & 15))] =
              f2bf(accs[i][nt][r]);
    }
    asm volatile("s_waitcnt lgkmcnt(0)" ::: "memory");  // P writes visible to own wave's reads

    // O += P V
    #pragma unroll
    for (int s = 0; s < 2; s++) {
      bf16x8 bv[4];
      #pragma unroll
      for (int dt = 0; dt < 4; dt++)
        bv[dt] = *(const bf16x8*)&V_[swz(dt * 16 + (lane & 15), s * 32 + (lane >> 4) * 8)];
      #pragma unroll
      for (int i = 0; i < 2; i++) {
        bf16x8 ap = *(const bf16x8*)&Ps[w][swz(i * 16 + (lane & 15), s * 32 + (lane >> 4) * 8)];
        #pragma unroll
        for (int dt = 0; dt < 4; dt++)
          acc_o[i][dt] = mfma16(ap, bv[dt], acc_o[i][dt]);
      }
    }
  }

  // epilogue: O / l -> att [b, n, h*64+d]
  #pragma unroll
  for (int i = 0; i < 2; i++) {
    float inv[4];
    #pragma unroll
    for (int r = 0; r < 4; r++) inv[r] = 1.0f / lrow[i][r];
    #pragma unroll
    for (int dt = 0; dt < 4; dt++)
      #pragma unroll
      for (int r = 0; r < 4; r++) {
        int row = q0 + w * 32 + i * 16 + (lane >> 4) * 4 + r;
        int col = h * 64 + dt * 16 + (lane & 15);
        Ob[((size_t)b * 1024 + row) * 1024 + col] = f2bf(acc_o[i][dt][r] * inv[r]);
      }
  }
}

// ---------------- launch ----------------
extern "C" void kernel_launch(void* const* d_in, const int* in_sizes, int n_in,
                              void* d_out, int out_size, void* d_ws, size_t ws_size,
                              hipStream_t stream) {
  const float* x     = (const float*)d_in[0];
  const float* temb  = (const float*)d_in[1];
  const float* cos_y = (const float*)d_in[2];
  const float* sin_y = (const float*)d_in[3];
  const float* cos_x = (const float*)d_in[4];
  const float* sin_x = (const float*)d_in[5];
  const float* Wqkv  = (const float*)d_in[6];
  const float* bqkv  = (const float*)d_in[7];
  const float* Wt    = (const float*)d_in[8];
  const float* bt    = (const float*)d_in[9];
  const float* Wp    = (const float*)d_in[10];
  const float* bp    = (const float*)d_in[11];
  const float* qn_w  = (const float*)d_in[12];
  const float* kn_w  = (const float*)d_in[13];
  float* out = (float*)d_out;

  char* ws = (char*)d_ws;
  u16*   x_bf  = (u16*)(ws);                  // 16 MB; reused as att after QKV GEMM
  u16*   WqkvT = (u16*)(ws + 16777216);       // 6 MB
  u16*   WpT   = (u16*)(ws + 23068672);       // 2 MB
  float* tcomb = (float*)(ws + 25165824);     // 96 KB
  u16*   qkv   = (u16*)(ws + 25264128);       // 48 MB
  u16*   Qb    = (u16*)(ws + 75595776);       // 16 MB
  u16*   Kb    = (u16*)(ws + 92372992);       // 16 MB
  u16*   VTb   = (u16*)(ws + 109150208);      // 16 MB
  u16*   att   = x_bf;

  k_cvt<<<8192, 256, 0, stream>>>(x, x_bf, 8192 * 1024 / 4);
  k_transpose<<<dim3(48, 16), 256, 0, stream>>>(Wqkv, WqkvT, 1024, 3072);
  k_transpose<<<dim3(16, 16), 256, 0, stream>>>(Wp, WpT, 1024, 1024);
  k_temb<<<dim3(12, 8), 256, 0, stream>>>(temb, Wt, bt, bqkv, tcomb);
  k_gemm<0><<<dim3(24, 64), 256, 0, stream>>>(x_bf, WqkvT, qkv, nullptr, tcomb, 1024, 3072);
  k_rrv<<<dim3(16, 16, 8), 256, 0, stream>>>(qkv, cos_y, sin_y, cos_x, sin_x,
                                             qn_w, kn_w, Qb, Kb, VTb);
  k_attn<<<dim3(128, 8), 256, 0, stream>>>(Qb, Kb, VTb, att);  // 8 q-tiles of 128 (R2 bug: was 4)
  k_gemm<1><<<dim3(8, 64), 256, 0, stream>>>(att, WpT, nullptr, out, bp, 1024, 1024);
}

// Round 4
// 353.238 us; speedup vs baseline: 1.2075x; 1.1601x over previous
//
#include <hip/hip_runtime.h>
#include <cstdint>

typedef unsigned short u16;
typedef __bf16 bf16x8 __attribute__((ext_vector_type(8)));
typedef float f32x4 __attribute__((ext_vector_type(4)));

__device__ __forceinline__ u16 f2bf(float f) {
  __bf16 h = (__bf16)f;               // HW v_cvt (RNE) on gfx950
  return __builtin_bit_cast(u16, h);
}
__device__ __forceinline__ float bf2f(u16 u) {
  union { uint32_t u; float f; } v; v.u = ((uint32_t)u) << 16;
  return v.f;
}

// async global->LDS, 16B per lane. LDS dest is wave-uniform base + lane*16.
__device__ __forceinline__ void gload16(const void* g, const void* l) {
  __builtin_amdgcn_global_load_lds(
      (const __attribute__((address_space(1))) uint32_t*)(uintptr_t)g,
      (__attribute__((address_space(3))) uint32_t*)(uintptr_t)l, 16, 0, 0);
}

__device__ __forceinline__ f32x4 mfma16(bf16x8 a, bf16x8 b, f32x4 c) {
  return __builtin_amdgcn_mfma_f32_16x16x32_bf16(a, b, c, 0, 0, 0);
}

// swizzled LDS offset for logical (row, col) in a [*][64] bf16 tile:
// 16B chunks XORed by row&7 -> conflict-free b128 reads (verified: 0 conflicts R1/R3).
__device__ __forceinline__ int swz(int row, int col) {
  return row * 64 + ((((col >> 3) ^ (row & 7)) << 3) | (col & 7));
}

// ---------------- convert fp32 -> bf16 (vectorized) ----------------
__global__ __launch_bounds__(256)
void k_cvt(const float* __restrict__ src, u16* __restrict__ dst, int n4) {
  int i = blockIdx.x * 256 + threadIdx.x;
  if (i >= n4) return;
  float4 v = ((const float4*)src)[i];
  union { u16 s[4]; uint2 u; } o;
  o.s[0] = f2bf(v.x); o.s[1] = f2bf(v.y); o.s[2] = f2bf(v.z); o.s[3] = f2bf(v.w);
  ((uint2*)dst)[i] = o.u;
}

// ------------- transpose fp32 [R][C] -> bf16 [C][R] (64x64 tiles) -------------
__global__ __launch_bounds__(256)
void k_transpose(const float* __restrict__ src, u16* __restrict__ dst, int R, int Cc) {
  __shared__ u16 t[64 * 66];
  int r0 = blockIdx.y * 64, c0 = blockIdx.x * 64;
  #pragma unroll
  for (int i = 0; i < 16; i++) {
    int e = i * 256 + threadIdx.x;
    int rl = e >> 6, cl = e & 63;
    t[cl * 66 + rl] = f2bf(src[(size_t)(r0 + rl) * Cc + c0 + cl]);
  }
  __syncthreads();
  #pragma unroll
  for (int i = 0; i < 16; i++) {
    int e = i * 256 + threadIdx.x;
    int ro = e >> 6, co = e & 63;
    dst[(size_t)(c0 + ro) * R + r0 + co] = t[ro * 66 + co];
  }
}

// ---------------- tcomb[b][j] = temb[b]@Wt[:,j] + bt[j] + bqkv[j] ----------------
__global__ __launch_bounds__(256)
void k_temb(const float* __restrict__ temb, const float* __restrict__ Wt,
            const float* __restrict__ bt, const float* __restrict__ bqkv,
            float* __restrict__ tcomb) {
  int j = blockIdx.x * 256 + threadIdx.x;   // 0..3071
  int b = blockIdx.y;
  const float* tb = temb + b * 1024;
  float a0 = 0.f, a1 = 0.f, a2 = 0.f, a3 = 0.f;
  for (int k = 0; k < 1024; k += 4) {
    a0 += tb[k]     * Wt[(size_t)k * 3072 + j];
    a1 += tb[k + 1] * Wt[(size_t)(k + 1) * 3072 + j];
    a2 += tb[k + 2] * Wt[(size_t)(k + 2) * 3072 + j];
    a3 += tb[k + 3] * Wt[(size_t)(k + 3) * 3072 + j];
  }
  tcomb[b * 3072 + j] = (a0 + a1) + (a2 + a3) + bt[j] + bqkv[j];
}

// ---------------- bf16 MFMA GEMM: C[M][Ntot] = A[M][K] @ Bt[N][K]^T ----------------
template <int MODE>
__global__ __launch_bounds__(256, 2)
void k_gemm(const u16* __restrict__ A, const u16* __restrict__ Bt,
            u16* __restrict__ outb, float* __restrict__ outf,
            const float* __restrict__ bias, int K, int Ntot) {
  __shared__ u16 As[128 * 32];
  __shared__ u16 Bs[128 * 32];
  const int m0 = blockIdx.y * 128;
  const int n0 = blockIdx.x * 128;
  const int lane = threadIdx.x & 63;
  const int w = threadIdx.x >> 6;
  const int wm = (w & 1) * 64;
  const int wn = (w >> 1) * 64;

  f32x4 acc[4][4];
  #pragma unroll
  for (int i = 0; i < 4; i++)
    #pragma unroll
    for (int j = 0; j < 4; j++) acc[i][j] = (f32x4){0.f, 0.f, 0.f, 0.f};

  const int rA = lane >> 2;
  const int cA = (lane & 3) * 8;
  const u16* Ag = A + (size_t)(m0 + rA) * K + cA;
  const u16* Bg = Bt + (size_t)(n0 + rA) * K + cA;

  for (int k0 = 0; k0 < K; k0 += 32) {
    #pragma unroll
    for (int tt = 0; tt < 2; tt++) {
      int t = 2 * w + tt;
      gload16(Ag + (size_t)(16 * t) * K + k0, &As[t * 512]);
      gload16(Bg + (size_t)(16 * t) * K + k0, &Bs[t * 512]);
    }
    __syncthreads();
    bf16x8 af[4], bfr[4];
    #pragma unroll
    for (int i = 0; i < 4; i++)
      af[i] = *(const bf16x8*)&As[(wm + 16 * i + (lane & 15)) * 32 + (lane >> 4) * 8];
    #pragma unroll
    for (int j = 0; j < 4; j++)
      bfr[j] = *(const bf16x8*)&Bs[(wn + 16 * j + (lane & 15)) * 32 + (lane >> 4) * 8];
    #pragma unroll
    for (int i = 0; i < 4; i++)
      #pragma unroll
      for (int j = 0; j < 4; j++)
        acc[i][j] = mfma16(af[i], bfr[j], acc[i][j]);
    __syncthreads();
  }

  const int rl = (lane >> 4) * 4;
  const int cl = lane & 15;
  #pragma unroll
  for (int i = 0; i < 4; i++) {
    #pragma unroll
    for (int j = 0; j < 4; j++) {
      #pragma unroll
      for (int r = 0; r < 4; r++) {
        int grow = m0 + wm + 16 * i + rl + r;
        int gcol = n0 + wn + 16 * j + cl;
        float v = acc[i][j][r];
        if (MODE == 0) {
          int b = grow >> 10;
          v += bias[b * Ntot + gcol];
          outb[(size_t)grow * Ntot + gcol] = f2bf(v);
        } else {
          v += bias[gcol];
          outf[(size_t)grow * Ntot + gcol] = v;
        }
      }
    }
  }
}

// ------- fused per-head RMSNorm + axial RoPE (q,k) + V transpose -------
// Q output pre-scaled by log2(e)/sqrt(64) so attention scores are in the
// exp2 domain directly (softmax(s) == normalized exp2(s*log2e)).
__global__ __launch_bounds__(256)
void k_rrv(const u16* __restrict__ qkv,
           const float* __restrict__ cos_y, const float* __restrict__ sin_y,
           const float* __restrict__ cos_x, const float* __restrict__ sin_x,
           const float* __restrict__ qn_w, const float* __restrict__ kn_w,
           u16* __restrict__ Qo, u16* __restrict__ Ko, u16* __restrict__ VT) {
  __shared__ u16 t[64 * 68];
  const int n0 = blockIdx.x * 64, h = blockIdx.y, b = blockIdx.z;
  const int bh = b * 16 + h;
  const int lane = threadIdx.x & 63, w = threadIdx.x >> 6;
  const int l15 = lane & 15, lg = lane >> 4;
  float4 qw = *(const float4*)(qn_w + l15 * 4);
  float4 kw = *(const float4*)(kn_w + l15 * 4);
  const float sgn = (lane & 4) ? 1.0f : -1.0f;   // rotate partner is d^16 within each 32-half
  const float* ct = (lane & 8) ? cos_x : cos_y;
  const float* st = (lane & 8) ? sin_x : sin_y;
  const float QSCALE = 0.18033688011112042f;     // log2(e)/8

  #pragma unroll
  for (int rr = 0; rr < 4; rr++) {
    int row = n0 + w * 16 + rr * 4 + lg;
    size_t src = (size_t)(b * 1024 + row) * 3072 + h * 64 + l15 * 4;
    uint2 qu = *(const uint2*)(qkv + src);
    uint2 ku = *(const uint2*)(qkv + src + 1024);
    float q[4], k[4];
    q[0] = bf2f((u16)qu.x); q[1] = bf2f((u16)(qu.x >> 16));
    q[2] = bf2f((u16)qu.y); q[3] = bf2f((u16)(qu.y >> 16));
    k[0] = bf2f((u16)ku.x); k[1] = bf2f((u16)(ku.x >> 16));
    k[2] = bf2f((u16)ku.y); k[3] = bf2f((u16)(ku.y >> 16));
    float sq = q[0]*q[0] + q[1]*q[1] + q[2]*q[2] + q[3]*q[3];
    float sk = k[0]*k[0] + k[1]*k[1] + k[2]*k[2] + k[3]*k[3];
    #pragma unroll
    for (int m = 1; m < 16; m <<= 1) {
      sq += __shfl_xor(sq, m);
      sk += __shfl_xor(sk, m);
    }
    float rq = rsqrtf(sq * (1.0f / 64.0f) + 1e-6f);
    float rk = rsqrtf(sk * (1.0f / 64.0f) + 1e-6f);
    float4 cc = *(const float4*)(ct + (size_t)row * 32 + (lane & 7) * 4);
    float4 ss = *(const float4*)(st + (size_t)row * 32 + (lane & 7) * 4);
    float qn[4], kn[4];
    qn[0] = q[0]*rq*qw.x; qn[1] = q[1]*rq*qw.y; qn[2] = q[2]*rq*qw.z; qn[3] = q[3]*rq*qw.w;
    kn[0] = k[0]*rk*kw.x; kn[1] = k[1]*rk*kw.y; kn[2] = k[2]*rk*kw.z; kn[3] = k[3]*rk*kw.w;
    float c[4] = {cc.x, cc.y, cc.z, cc.w};
    float s[4] = {ss.x, ss.y, ss.z, ss.w};
    union { u16 e[4]; uint2 u; } oq, ok;
    #pragma unroll
    for (int j = 0; j < 4; j++) {
      float qp = __shfl_xor(qn[j], 4);   // partner chunk (l15^4) == d^16
      float kp = __shfl_xor(kn[j], 4);
      oq.e[j] = f2bf((qn[j] * c[j] + sgn * qp * s[j]) * QSCALE);
      ok.e[j] = f2bf(kn[j] * c[j] + sgn * kp * s[j]);
    }
    size_t dst = ((size_t)bh * 1024 + row) * 64 + l15 * 4;
    *(uint2*)(Qo + dst) = oq.u;
    *(uint2*)(Ko + dst) = ok.u;
  }

  // V transpose: qkv v-slice [n][d] -> VT [bh][d][n]
  #pragma unroll
  for (int i = 0; i < 4; i++) {
    int e = i * 256 + threadIdx.x;
    int n = e >> 4, dc = e & 15;
    uint2 v = *(const uint2*)(qkv + (size_t)(b * 1024 + n0 + n) * 3072 + 2048 + h * 64 + dc * 4);
    t[(dc * 4 + 0) * 68 + n] = (u16)v.x;
    t[(dc * 4 + 1) * 68 + n] = (u16)(v.x >> 16);
    t[(dc * 4 + 2) * 68 + n] = (u16)v.y;
    t[(dc * 4 + 3) * 68 + n] = (u16)(v.y >> 16);
  }
  __syncthreads();
  #pragma unroll
  for (int i = 0; i < 4; i++) {
    int e = i * 256 + threadIdx.x;
    int d = e >> 4, nc = e & 15;
    const u16* p = &t[d * 68 + nc * 4];
    uint2 o;
    o.x = (uint32_t)p[0] | ((uint32_t)p[1] << 16);
    o.y = (uint32_t)p[2] | ((uint32_t)p[3] << 16);
    *(uint2*)(VT + ((size_t)bh * 64 + d) * 1024 + n0 + nc * 4) = o;
  }
}

// ---------------- flash attention, 128 q-rows/block, dbuf K/V, 1 barrier/iter ----------------
// Fixed-max softmax: scores s2 = (q.k)*log2e/8 are bounded (|s|<=8 by
// Cauchy-Schwarz on RMS-normalized q,k => |s2|<=11.6, exp2<=3e3, l<=3e6 fp32-safe),
// so no running max / alpha rescale; l reduced once in epilogue.
__global__ __launch_bounds__(256, 2)
void k_attn(const u16* __restrict__ Q, const u16* __restrict__ Kb,
            const u16* __restrict__ VT, u16* __restrict__ Ob) {
  __shared__ u16 Ks[2][4096], VTs[2][4096], Ps[4][2048];
  const int lane = threadIdx.x & 63;
  const int w = threadIdx.x >> 6;
  const int bh = blockIdx.x;          // b*16+h : q-tiles of one bh co-locate on an XCD
  const int qt = blockIdx.y;
  const int b = bh >> 4, h = bh & 15;
  const size_t base = (size_t)bh * 65536;
  const int q0 = qt * 128;
  const int scol = ((lane & 7) ^ (lane >> 3)) * 8;  // XOR-swizzled source chunk for staging
  const int lr = lane >> 3;

  // Q fragments in registers (pre-scaled by log2e/8 in k_rrv)
  bf16x8 aq[2][2];
  #pragma unroll
  for (int i = 0; i < 2; i++)
    #pragma unroll
    for (int s = 0; s < 2; s++)
      aq[i][s] = *(const bf16x8*)(Q + base +
          (size_t)(q0 + w * 32 + i * 16 + (lane & 15)) * 64 + s * 32 + (lane >> 4) * 8);

  f32x4 acc_o[2][4];
  float lpar[2][4];
  #pragma unroll
  for (int i = 0; i < 2; i++)
    #pragma unroll
    for (int r = 0; r < 4; r++) {
      acc_o[i][r] = (f32x4){0.f, 0.f, 0.f, 0.f};
      lpar[i][r] = 0.f;
    }

  // stage j-tile 0 into buf 0
  #pragma unroll
  for (int tt = 0; tt < 2; tt++) {
    int t = w * 2 + tt;
    gload16(Kb + base + (size_t)(8 * t + lr) * 64 + scol, &Ks[0][t * 512]);
    gload16(VT + base + (size_t)(8 * t + lr) * 1024 + scol, &VTs[0][t * 512]);
  }

  for (int it = 0; it < 16; it++) {
    __syncthreads();                 // staging of cur complete; all readers of nxt (prev iter) done
    const int cur = it & 1;
    if (it < 15) {                   // prefetch next tile; latency hidden behind this iter's compute
      const int nxt = cur ^ 1;
      const int j1 = (it + 1) * 64;
      #pragma unroll
      for (int tt = 0; tt < 2; tt++) {
        int t = w * 2 + tt;
        gload16(Kb + base + (size_t)(j1 + 8 * t + lr) * 64 + scol, &Ks[nxt][t * 512]);
        gload16(VT + base + (size_t)(8 * t + lr) * 1024 + j1 + scol, &VTs[nxt][t * 512]);
      }
    }
    const u16* K_ = Ks[cur];
    const u16* V_ = VTs[cur];

    // S2 = Qhat K^T (already in exp2 domain)
    f32x4 accs[2][4];
    #pragma unroll
    for (int i = 0; i < 2; i++)
      #pragma unroll
      for (int nt = 0; nt < 4; nt++) accs[i][nt] = (f32x4){0.f, 0.f, 0.f, 0.f};
    #pragma unroll
    for (int s = 0; s < 2; s++) {
      bf16x8 bk[4];
      #pragma unroll
      for (int nt = 0; nt < 4; nt++)
        bk[nt] = *(const bf16x8*)&K_[swz(nt * 16 + (lane & 15), s * 32 + (lane >> 4) * 8)];
      #pragma unroll
      for (int i = 0; i < 2; i++)
        #pragma unroll
        for (int nt = 0; nt < 4; nt++)
          accs[i][nt] = mfma16(aq[i][s], bk[nt], accs[i][nt]);
    }

    // P = exp2(S2); accumulate per-lane l partials; P -> wave-private LDS strip
    #pragma unroll
    for (int i = 0; i < 2; i++) {
      #pragma unroll
      for (int nt = 0; nt < 4; nt++) {
        #pragma unroll
        for (int r = 0; r < 4; r++) {
          float p = __builtin_amdgcn_exp2f(accs[i][nt][r]);
          lpar[i][r] += p;
          Ps[w][swz(i * 16 + (lane >> 4) * 4 + r, nt * 16 + (lane & 15))] = f2bf(p);
        }
      }
    }
    asm volatile("s_waitcnt lgkmcnt(0)" ::: "memory");  // P writes visible to own wave's reads

    // O += P V
    #pragma unroll
    for (int s = 0; s < 2; s++) {
      bf16x8 bv[4];
      #pragma unroll
      for (int dt = 0; dt < 4; dt++)
        bv[dt] = *(const bf16x8*)&V_[swz(dt * 16 + (lane & 15), s * 32 + (lane >> 4) * 8)];
      #pragma unroll
      for (int i = 0; i < 2; i++) {
        bf16x8 ap = *(const bf16x8*)&Ps[w][swz(i * 16 + (lane & 15), s * 32 + (lane >> 4) * 8)];
        #pragma unroll
        for (int dt = 0; dt < 4; dt++)
          acc_o[i][dt] = mfma16(ap, bv[dt], acc_o[i][dt]);
      }
    }
  }

  // epilogue: reduce l over the 16-lane col group (once), O/l -> att [b, n, h*64+d]
  #pragma unroll
  for (int i = 0; i < 2; i++) {
    float inv[4];
    #pragma unroll
    for (int r = 0; r < 4; r++) {
      float l = lpar[i][r];
      #pragma unroll
      for (int m = 1; m < 16; m <<= 1) l += __shfl_xor(l, m);
      inv[r] = 1.0f / l;
    }
    #pragma unroll
    for (int dt = 0; dt < 4; dt++)
      #pragma unroll
      for (int r = 0; r < 4; r++) {
        int row = q0 + w * 32 + i * 16 + (lane >> 4) * 4 + r;
        int col = h * 64 + dt * 16 + (lane & 15);
        Ob[((size_t)b * 1024 + row) * 1024 + col] = f2bf(acc_o[i][dt][r] * inv[r]);
      }
  }
}

// ---------------- launch ----------------
extern "C" void kernel_launch(void* const* d_in, const int* in_sizes, int n_in,
                              void* d_out, int out_size, void* d_ws, size_t ws_size,
                              hipStream_t stream) {
  const float* x     = (const float*)d_in[0];
  const float* temb  = (const float*)d_in[1];
  const float* cos_y = (const float*)d_in[2];
  const float* sin_y = (const float*)d_in[3];
  const float* cos_x = (const float*)d_in[4];
  const float* sin_x = (const float*)d_in[5];
  const float* Wqkv  = (const float*)d_in[6];
  const float* bqkv  = (const float*)d_in[7];
  const float* Wt    = (const float*)d_in[8];
  const float* bt    = (const float*)d_in[9];
  const float* Wp    = (const float*)d_in[10];
  const float* bp    = (const float*)d_in[11];
  const float* qn_w  = (const float*)d_in[12];
  const float* kn_w  = (const float*)d_in[13];
  float* out = (float*)d_out;

  char* ws = (char*)d_ws;
  u16*   x_bf  = (u16*)(ws);                  // 16 MB; reused as att after QKV GEMM
  u16*   WqkvT = (u16*)(ws + 16777216);       // 6 MB
  u16*   WpT   = (u16*)(ws + 23068672);       // 2 MB
  float* tcomb = (float*)(ws + 25165824);     // 96 KB
  u16*   qkv   = (u16*)(ws + 25264128);       // 48 MB
  u16*   Qb    = (u16*)(ws + 75595776);       // 16 MB
  u16*   Kb    = (u16*)(ws + 92372992);       // 16 MB
  u16*   VTb   = (u16*)(ws + 109150208);      // 16 MB
  u16*   att   = x_bf;

  k_cvt<<<8192, 256, 0, stream>>>(x, x_bf, 8192 * 1024 / 4);
  k_transpose<<<dim3(48, 16), 256, 0, stream>>>(Wqkv, WqkvT, 1024, 3072);
  k_transpose<<<dim3(16, 16), 256, 0, stream>>>(Wp, WpT, 1024, 1024);
  k_temb<<<dim3(12, 8), 256, 0, stream>>>(temb, Wt, bt, bqkv, tcomb);
  k_gemm<0><<<dim3(24, 64), 256, 0, stream>>>(x_bf, WqkvT, qkv, nullptr, tcomb, 1024, 3072);
  k_rrv<<<dim3(16, 16, 8), 256, 0, stream>>>(qkv, cos_y, sin_y, cos_x, sin_x,
                                             qn_w, kn_w, Qb, Kb, VTb);
  k_attn<<<dim3(128, 8), 256, 0, stream>>>(Qb, Kb, VTb, att);
  k_gemm<1><<<dim3(8, 64), 256, 0, stream>>>(att, WpT, nullptr, out, bp, 1024, 1024);
}

// Round 5
// 349.984 us; speedup vs baseline: 1.2187x; 1.0093x over previous
//
#include <hip/hip_runtime.h>
#include <cstdint>

typedef unsigned short u16;
typedef __bf16 bf16x8 __attribute__((ext_vector_type(8)));
typedef float f32x4 __attribute__((ext_vector_type(4)));

__device__ __forceinline__ u16 f2bf(float f) {
  __bf16 h = (__bf16)f;               // HW v_cvt (RNE) on gfx950
  return __builtin_bit_cast(u16, h);
}
__device__ __forceinline__ float bf2f(u16 u) {
  union { uint32_t u; float f; } v; v.u = ((uint32_t)u) << 16;
  return v.f;
}

// async global->LDS, 16B per lane. LDS dest is wave-uniform base + lane*16.
__device__ __forceinline__ void gload16(const void* g, const void* l) {
  __builtin_amdgcn_global_load_lds(
      (const __attribute__((address_space(1))) uint32_t*)(uintptr_t)g,
      (__attribute__((address_space(3))) uint32_t*)(uintptr_t)l, 16, 0, 0);
}

__device__ __forceinline__ f32x4 mfma16(bf16x8 a, bf16x8 b, f32x4 c) {
  return __builtin_amdgcn_mfma_f32_16x16x32_bf16(a, b, c, 0, 0, 0);
}

// swizzled LDS offset for logical (row, col) in a [*][64] bf16 tile:
// 16B chunks XORed by row&7 -> conflict-free b128 reads (verified: 0 conflicts R1/R3).
__device__ __forceinline__ int swz(int row, int col) {
  return row * 64 + ((((col >> 3) ^ (row & 7)) << 3) | (col & 7));
}

// ---------------- convert fp32 -> bf16 (vectorized) ----------------
__global__ __launch_bounds__(256)
void k_cvt(const float* __restrict__ src, u16* __restrict__ dst, int n4) {
  int i = blockIdx.x * 256 + threadIdx.x;
  if (i >= n4) return;
  float4 v = ((const float4*)src)[i];
  union { u16 s[4]; uint2 u; } o;
  o.s[0] = f2bf(v.x); o.s[1] = f2bf(v.y); o.s[2] = f2bf(v.z); o.s[3] = f2bf(v.w);
  ((uint2*)dst)[i] = o.u;
}

// ------------- transpose fp32 [R][C] -> bf16 [C][R] (64x64 tiles) -------------
__global__ __launch_bounds__(256)
void k_transpose(const float* __restrict__ src, u16* __restrict__ dst, int R, int Cc) {
  __shared__ u16 t[64 * 66];
  int r0 = blockIdx.y * 64, c0 = blockIdx.x * 64;
  #pragma unroll
  for (int i = 0; i < 16; i++) {
    int e = i * 256 + threadIdx.x;
    int rl = e >> 6, cl = e & 63;
    t[cl * 66 + rl] = f2bf(src[(size_t)(r0 + rl) * Cc + c0 + cl]);
  }
  __syncthreads();
  #pragma unroll
  for (int i = 0; i < 16; i++) {
    int e = i * 256 + threadIdx.x;
    int ro = e >> 6, co = e & 63;
    dst[(size_t)(c0 + ro) * R + r0 + co] = t[ro * 66 + co];
  }
}

// ---------------- tcomb[b][j] = temb[b]@Wt[:,j] + bt[j] + bqkv[j] ----------------
__global__ __launch_bounds__(256)
void k_temb(const float* __restrict__ temb, const float* __restrict__ Wt,
            const float* __restrict__ bt, const float* __restrict__ bqkv,
            float* __restrict__ tcomb) {
  int j = blockIdx.x * 256 + threadIdx.x;   // 0..3071
  int b = blockIdx.y;
  const float* tb = temb + b * 1024;
  float a0 = 0.f, a1 = 0.f, a2 = 0.f, a3 = 0.f;
  for (int k = 0; k < 1024; k += 4) {
    a0 += tb[k]     * Wt[(size_t)k * 3072 + j];
    a1 += tb[k + 1] * Wt[(size_t)(k + 1) * 3072 + j];
    a2 += tb[k + 2] * Wt[(size_t)(k + 2) * 3072 + j];
    a3 += tb[k + 3] * Wt[(size_t)(k + 3) * 3072 + j];
  }
  tcomb[b * 3072 + j] = (a0 + a1) + (a2 + a3) + bt[j] + bqkv[j];
}

// ------------- bf16 MFMA GEMM: C[M][Ntot] = A[M][K] @ Bt[N][K]^T -------------
// Block 256M x 128N, 4 waves, wave tile 64M x 128N (reads/MFMA = 0.375).
// Double-buffered LDS, one barrier/iter, prefetch issued after barrier.
// LDS chunk swizzle: 16B chunk cp = c ^ ((row>>1)&3) -> 2-way (free) b128 reads.
template <int MODE>
__global__ __launch_bounds__(256, 2)
void k_gemm(const u16* __restrict__ A, const u16* __restrict__ Bt,
            u16* __restrict__ outb, float* __restrict__ outf,
            const float* __restrict__ bias, int K, int Ntot) {
  __shared__ u16 As[2][8192];   // 256 rows x 32 (K32) u16, swizzled
  __shared__ u16 Bs[2][4096];   // 128 rows x 32
  const int m0 = blockIdx.y * 256;
  const int n0 = blockIdx.x * 128;
  const int lane = threadIdx.x & 63;
  const int w = threadIdx.x >> 6;
  const int l15 = lane & 15;
  // fragment read chunk offset (u16): cp = g ^ ((row>>1)&3), row bits1-2 == lane bits1-2
  const int fo = (((lane >> 4) ^ ((lane >> 1) & 3)) << 3);
  // staging: instr t covers rows 16t+(lane>>2); LDS slot cp=lane&3 holds chunk c=cp^((lane>>3)&3)
  const int srow = lane >> 2;
  const int schunk = (((lane & 3) ^ ((lane >> 3) & 3)) << 3);

  f32x4 acc[4][8];
  #pragma unroll
  for (int i = 0; i < 4; i++)
    #pragma unroll
    for (int j = 0; j < 8; j++) acc[i][j] = (f32x4){0.f, 0.f, 0.f, 0.f};

  const u16* Ag = A + (size_t)(m0 + srow) * K + schunk;
  const u16* Bg = Bt + (size_t)(n0 + srow) * K + schunk;

  const int iters = K >> 5;
  // stage K-tile 0 into buf 0
  #pragma unroll
  for (int tt = 0; tt < 4; tt++) {
    int t = w * 4 + tt;
    gload16(Ag + (size_t)(16 * t) * K, &As[0][t * 512]);
  }
  #pragma unroll
  for (int tt = 0; tt < 2; tt++) {
    int t = w * 2 + tt;
    gload16(Bg + (size_t)(16 * t) * K, &Bs[0][t * 512]);
  }

  for (int it = 0; it < iters; it++) {
    __syncthreads();               // cur staged; all readers of nxt-slot (prev iter) done
    const int cur = it & 1;
    if (it + 1 < iters) {          // prefetch next K-tile; lands during this iter's compute
      const int nxt = cur ^ 1;
      const int k1 = (it + 1) << 5;
      #pragma unroll
      for (int tt = 0; tt < 4; tt++) {
        int t = w * 4 + tt;
        gload16(Ag + (size_t)(16 * t) * K + k1, &As[nxt][t * 512]);
      }
      #pragma unroll
      for (int tt = 0; tt < 2; tt++) {
        int t = w * 2 + tt;
        gload16(Bg + (size_t)(16 * t) * K + k1, &Bs[nxt][t * 512]);
      }
    }
    bf16x8 af[4], bfr[8];
    #pragma unroll
    for (int i = 0; i < 4; i++)
      af[i] = *(const bf16x8*)&As[cur][(w * 64 + 16 * i + l15) * 32 + fo];
    #pragma unroll
    for (int j = 0; j < 8; j++)
      bfr[j] = *(const bf16x8*)&Bs[cur][(16 * j + l15) * 32 + fo];
    #pragma unroll
    for (int i = 0; i < 4; i++)
      #pragma unroll
      for (int j = 0; j < 8; j++)
        acc[i][j] = mfma16(af[i], bfr[j], acc[i][j]);
  }

  const int rl = (lane >> 4) * 4;
  #pragma unroll
  for (int i = 0; i < 4; i++) {
    #pragma unroll
    for (int j = 0; j < 8; j++) {
      #pragma unroll
      for (int r = 0; r < 4; r++) {
        int grow = m0 + w * 64 + 16 * i + rl + r;
        int gcol = n0 + 16 * j + l15;
        float v = acc[i][j][r];
        if (MODE == 0) {
          int b = grow >> 10;
          v += bias[b * Ntot + gcol];
          outb[(size_t)grow * Ntot + gcol] = f2bf(v);
        } else {
          v += bias[gcol];
          outf[(size_t)grow * Ntot + gcol] = v;
        }
      }
    }
  }
}

// ------- fused per-head RMSNorm + axial RoPE (q,k) + V transpose -------
// Q output pre-scaled by log2(e)/sqrt(64) so attention scores are in the
// exp2 domain directly (softmax(s) == normalized exp2(s*log2e)).
__global__ __launch_bounds__(256)
void k_rrv(const u16* __restrict__ qkv,
           const float* __restrict__ cos_y, const float* __restrict__ sin_y,
           const float* __restrict__ cos_x, const float* __restrict__ sin_x,
           const float* __restrict__ qn_w, const float* __restrict__ kn_w,
           u16* __restrict__ Qo, u16* __restrict__ Ko, u16* __restrict__ VT) {
  __shared__ u16 t[64 * 68];
  const int n0 = blockIdx.x * 64, h = blockIdx.y, b = blockIdx.z;
  const int bh = b * 16 + h;
  const int lane = threadIdx.x & 63, w = threadIdx.x >> 6;
  const int l15 = lane & 15, lg = lane >> 4;
  float4 qw = *(const float4*)(qn_w + l15 * 4);
  float4 kw = *(const float4*)(kn_w + l15 * 4);
  const float sgn = (lane & 4) ? 1.0f : -1.0f;   // rotate partner is d^16 within each 32-half
  const float* ct = (lane & 8) ? cos_x : cos_y;
  const float* st = (lane & 8) ? sin_x : sin_y;
  const float QSCALE = 0.18033688011112042f;     // log2(e)/8

  #pragma unroll
  for (int rr = 0; rr < 4; rr++) {
    int row = n0 + w * 16 + rr * 4 + lg;
    size_t src = (size_t)(b * 1024 + row) * 3072 + h * 64 + l15 * 4;
    uint2 qu = *(const uint2*)(qkv + src);
    uint2 ku = *(const uint2*)(qkv + src + 1024);
    float q[4], k[4];
    q[0] = bf2f((u16)qu.x); q[1] = bf2f((u16)(qu.x >> 16));
    q[2] = bf2f((u16)qu.y); q[3] = bf2f((u16)(qu.y >> 16));
    k[0] = bf2f((u16)ku.x); k[1] = bf2f((u16)(ku.x >> 16));
    k[2] = bf2f((u16)ku.y); k[3] = bf2f((u16)(ku.y >> 16));
    float sq = q[0]*q[0] + q[1]*q[1] + q[2]*q[2] + q[3]*q[3];
    float sk = k[0]*k[0] + k[1]*k[1] + k[2]*k[2] + k[3]*k[3];
    #pragma unroll
    for (int m = 1; m < 16; m <<= 1) {
      sq += __shfl_xor(sq, m);
      sk += __shfl_xor(sk, m);
    }
    float rq = rsqrtf(sq * (1.0f / 64.0f) + 1e-6f);
    float rk = rsqrtf(sk * (1.0f / 64.0f) + 1e-6f);
    float4 cc = *(const float4*)(ct + (size_t)row * 32 + (lane & 7) * 4);
    float4 ss = *(const float4*)(st + (size_t)row * 32 + (lane & 7) * 4);
    float qn[4], kn[4];
    qn[0] = q[0]*rq*qw.x; qn[1] = q[1]*rq*qw.y; qn[2] = q[2]*rq*qw.z; qn[3] = q[3]*rq*qw.w;
    kn[0] = k[0]*rk*kw.x; kn[1] = k[1]*rk*kw.y; kn[2] = k[2]*rk*kw.z; kn[3] = k[3]*rk*kw.w;
    float c[4] = {cc.x, cc.y, cc.z, cc.w};
    float s[4] = {ss.x, ss.y, ss.z, ss.w};
    union { u16 e[4]; uint2 u; } oq, ok;
    #pragma unroll
    for (int j = 0; j < 4; j++) {
      float qp = __shfl_xor(qn[j], 4);   // partner chunk (l15^4) == d^16
      float kp = __shfl_xor(kn[j], 4);
      oq.e[j] = f2bf((qn[j] * c[j] + sgn * qp * s[j]) * QSCALE);
      ok.e[j] = f2bf(kn[j] * c[j] + sgn * kp * s[j]);
    }
    size_t dst = ((size_t)bh * 1024 + row) * 64 + l15 * 4;
    *(uint2*)(Qo + dst) = oq.u;
    *(uint2*)(Ko + dst) = ok.u;
  }

  // V transpose: qkv v-slice [n][d] -> VT [bh][d][n]
  #pragma unroll
  for (int i = 0; i < 4; i++) {
    int e = i * 256 + threadIdx.x;
    int n = e >> 4, dc = e & 15;
    uint2 v = *(const uint2*)(qkv + (size_t)(b * 1024 + n0 + n) * 3072 + 2048 + h * 64 + dc * 4);
    t[(dc * 4 + 0) * 68 + n] = (u16)v.x;
    t[(dc * 4 + 1) * 68 + n] = (u16)(v.x >> 16);
    t[(dc * 4 + 2) * 68 + n] = (u16)v.y;
    t[(dc * 4 + 3) * 68 + n] = (u16)(v.y >> 16);
  }
  __syncthreads();
  #pragma unroll
  for (int i = 0; i < 4; i++) {
    int e = i * 256 + threadIdx.x;
    int d = e >> 4, nc = e & 15;
    const u16* p = &t[d * 68 + nc * 4];
    uint2 o;
    o.x = (uint32_t)p[0] | ((uint32_t)p[1] << 16);
    o.y = (uint32_t)p[2] | ((uint32_t)p[3] << 16);
    *(uint2*)(VT + ((size_t)bh * 64 + d) * 1024 + n0 + nc * 4) = o;
  }
}

// ---------------- flash attention, 128 q-rows/block, dbuf K/V, 1 barrier/iter ----------------
// Fixed-max softmax: scores s2 = (q.k)*log2e/8 are bounded (|s|<=8 by
// Cauchy-Schwarz on RMS-normalized q,k => |s2|<=11.6, exp2<=3e3, l<=3e6 fp32-safe),
// so no running max / alpha rescale; l reduced once in epilogue.
__global__ __launch_bounds__(256, 2)
void k_attn(const u16* __restrict__ Q, const u16* __restrict__ Kb,
            const u16* __restrict__ VT, u16* __restrict__ Ob) {
  __shared__ u16 Ks[2][4096], VTs[2][4096], Ps[4][2048];
  const int lane = threadIdx.x & 63;
  const int w = threadIdx.x >> 6;
  const int bh = blockIdx.x;          // b*16+h : q-tiles of one bh co-locate on an XCD
  const int qt = blockIdx.y;
  const int b = bh >> 4, h = bh & 15;
  const size_t base = (size_t)bh * 65536;
  const int q0 = qt * 128;
  const int scol = ((lane & 7) ^ (lane >> 3)) * 8;  // XOR-swizzled source chunk for staging
  const int lr = lane >> 3;

  // Q fragments in registers (pre-scaled by log2e/8 in k_rrv)
  bf16x8 aq[2][2];
  #pragma unroll
  for (int i = 0; i < 2; i++)
    #pragma unroll
    for (int s = 0; s < 2; s++)
      aq[i][s] = *(const bf16x8*)(Q + base +
          (size_t)(q0 + w * 32 + i * 16 + (lane & 15)) * 64 + s * 32 + (lane >> 4) * 8);

  f32x4 acc_o[2][4];
  float lpar[2][4];
  #pragma unroll
  for (int i = 0; i < 2; i++)
    #pragma unroll
    for (int r = 0; r < 4; r++) {
      acc_o[i][r] = (f32x4){0.f, 0.f, 0.f, 0.f};
      lpar[i][r] = 0.f;
    }

  // stage j-tile 0 into buf 0
  #pragma unroll
  for (int tt = 0; tt < 2; tt++) {
    int t = w * 2 + tt;
    gload16(Kb + base + (size_t)(8 * t + lr) * 64 + scol, &Ks[0][t * 512]);
    gload16(VT + base + (size_t)(8 * t + lr) * 1024 + scol, &VTs[0][t * 512]);
  }

  for (int it = 0; it < 16; it++) {
    __syncthreads();                 // staging of cur complete; all readers of nxt (prev iter) done
    const int cur = it & 1;
    if (it < 15) {                   // prefetch next tile; latency hidden behind this iter's compute
      const int nxt = cur ^ 1;
      const int j1 = (it + 1) * 64;
      #pragma unroll
      for (int tt = 0; tt < 2; tt++) {
        int t = w * 2 + tt;
        gload16(Kb + base + (size_t)(j1 + 8 * t + lr) * 64 + scol, &Ks[nxt][t * 512]);
        gload16(VT + base + (size_t)(8 * t + lr) * 1024 + j1 + scol, &VTs[nxt][t * 512]);
      }
    }
    const u16* K_ = Ks[cur];
    const u16* V_ = VTs[cur];

    // S2 = Qhat K^T (already in exp2 domain)
    f32x4 accs[2][4];
    #pragma unroll
    for (int i = 0; i < 2; i++)
      #pragma unroll
      for (int nt = 0; nt < 4; nt++) accs[i][nt] = (f32x4){0.f, 0.f, 0.f, 0.f};
    #pragma unroll
    for (int s = 0; s < 2; s++) {
      bf16x8 bk[4];
      #pragma unroll
      for (int nt = 0; nt < 4; nt++)
        bk[nt] = *(const bf16x8*)&K_[swz(nt * 16 + (lane & 15), s * 32 + (lane >> 4) * 8)];
      #pragma unroll
      for (int i = 0; i < 2; i++)
        #pragma unroll
        for (int nt = 0; nt < 4; nt++)
          accs[i][nt] = mfma16(aq[i][s], bk[nt], accs[i][nt]);
    }

    // P = exp2(S2); accumulate per-lane l partials; P -> wave-private LDS strip
    #pragma unroll
    for (int i = 0; i < 2; i++) {
      #pragma unroll
      for (int nt = 0; nt < 4; nt++) {
        #pragma unroll
        for (int r = 0; r < 4; r++) {
          float p = __builtin_amdgcn_exp2f(accs[i][nt][r]);
          lpar[i][r] += p;
          Ps[w][swz(i * 16 + (lane >> 4) * 4 + r, nt * 16 + (lane & 15))] = f2bf(p);
        }
      }
    }
    asm volatile("s_waitcnt lgkmcnt(0)" ::: "memory");  // P writes visible to own wave's reads

    // O += P V
    #pragma unroll
    for (int s = 0; s < 2; s++) {
      bf16x8 bv[4];
      #pragma unroll
      for (int dt = 0; dt < 4; dt++)
        bv[dt] = *(const bf16x8*)&V_[swz(dt * 16 + (lane & 15), s * 32 + (lane >> 4) * 8)];
      #pragma unroll
      for (int i = 0; i < 2; i++) {
        bf16x8 ap = *(const bf16x8*)&Ps[w][swz(i * 16 + (lane & 15), s * 32 + (lane >> 4) * 8)];
        #pragma unroll
        for (int dt = 0; dt < 4; dt++)
          acc_o[i][dt] = mfma16(ap, bv[dt], acc_o[i][dt]);
      }
    }
  }

  // epilogue: reduce l over the 16-lane col group (once), O/l -> att [b, n, h*64+d]
  #pragma unroll
  for (int i = 0; i < 2; i++) {
    float inv[4];
    #pragma unroll
    for (int r = 0; r < 4; r++) {
      float l = lpar[i][r];
      #pragma unroll
      for (int m = 1; m < 16; m <<= 1) l += __shfl_xor(l, m);
      inv[r] = 1.0f / l;
    }
    #pragma unroll
    for (int dt = 0; dt < 4; dt++)
      #pragma unroll
      for (int r = 0; r < 4; r++) {
        int row = q0 + w * 32 + i * 16 + (lane >> 4) * 4 + r;
        int col = h * 64 + dt * 16 + (lane & 15);
        Ob[((size_t)b * 1024 + row) * 1024 + col] = f2bf(acc_o[i][dt][r] * inv[r]);
      }
  }
}

// ---------------- launch ----------------
extern "C" void kernel_launch(void* const* d_in, const int* in_sizes, int n_in,
                              void* d_out, int out_size, void* d_ws, size_t ws_size,
                              hipStream_t stream) {
  const float* x     = (const float*)d_in[0];
  const float* temb  = (const float*)d_in[1];
  const float* cos_y = (const float*)d_in[2];
  const float* sin_y = (const float*)d_in[3];
  const float* cos_x = (const float*)d_in[4];
  const float* sin_x = (const float*)d_in[5];
  const float* Wqkv  = (const float*)d_in[6];
  const float* bqkv  = (const float*)d_in[7];
  const float* Wt    = (const float*)d_in[8];
  const float* bt    = (const float*)d_in[9];
  const float* Wp    = (const float*)d_in[10];
  const float* bp    = (const float*)d_in[11];
  const float* qn_w  = (const float*)d_in[12];
  const float* kn_w  = (const float*)d_in[13];
  float* out = (float*)d_out;

  char* ws = (char*)d_ws;
  u16*   x_bf  = (u16*)(ws);                  // 16 MB; reused as att after QKV GEMM
  u16*   WqkvT = (u16*)(ws + 16777216);       // 6 MB
  u16*   WpT   = (u16*)(ws + 23068672);       // 2 MB
  float* tcomb = (float*)(ws + 25165824);     // 96 KB
  u16*   qkv   = (u16*)(ws + 25264128);       // 48 MB
  u16*   Qb    = (u16*)(ws + 75595776);       // 16 MB
  u16*   Kb    = (u16*)(ws + 92372992);       // 16 MB
  u16*   VTb   = (u16*)(ws + 109150208);      // 16 MB
  u16*   att   = x_bf;

  k_cvt<<<8192, 256, 0, stream>>>(x, x_bf, 8192 * 1024 / 4);
  k_transpose<<<dim3(48, 16), 256, 0, stream>>>(Wqkv, WqkvT, 1024, 3072);
  k_transpose<<<dim3(16, 16), 256, 0, stream>>>(Wp, WpT, 1024, 1024);
  k_temb<<<dim3(12, 8), 256, 0, stream>>>(temb, Wt, bt, bqkv, tcomb);
  k_gemm<0><<<dim3(24, 32), 256, 0, stream>>>(x_bf, WqkvT, qkv, nullptr, tcomb, 1024, 3072);
  k_rrv<<<dim3(16, 16, 8), 256, 0, stream>>>(qkv, cos_y, sin_y, cos_x, sin_x,
                                             qn_w, kn_w, Qb, Kb, VTb);
  k_attn<<<dim3(128, 8), 256, 0, stream>>>(Qb, Kb, VTb, att);
  k_gemm<1><<<dim3(8, 32), 256, 0, stream>>>(att, WpT, nullptr, out, bp, 1024, 1024);
}

// Round 6
// 300.667 us; speedup vs baseline: 1.4186x; 1.1640x over previous
//
#include <hip/hip_runtime.h>
#include <cstdint>

typedef unsigned short u16;
typedef __bf16 bf16x8 __attribute__((ext_vector_type(8)));
typedef float f32x4 __attribute__((ext_vector_type(4)));

__device__ __forceinline__ u16 f2bf(float f) {
  __bf16 h = (__bf16)f;               // HW v_cvt (RNE) on gfx950
  return __builtin_bit_cast(u16, h);
}
__device__ __forceinline__ float bf2f(u16 u) {
  union { uint32_t u; float f; } v; v.u = ((uint32_t)u) << 16;
  return v.f;
}

// async global->LDS, 16B per lane. LDS dest is wave-uniform base + lane*16.
__device__ __forceinline__ void gload16(const void* g, const void* l) {
  __builtin_amdgcn_global_load_lds(
      (const __attribute__((address_space(1))) uint32_t*)(uintptr_t)g,
      (__attribute__((address_space(3))) uint32_t*)(uintptr_t)l, 16, 0, 0);
}

__device__ __forceinline__ f32x4 mfma16(bf16x8 a, bf16x8 b, f32x4 c) {
  return __builtin_amdgcn_mfma_f32_16x16x32_bf16(a, b, c, 0, 0, 0);
}

// swizzled LDS offset for logical (row, col) in a [*][64] bf16 tile:
// 16B chunks XORed by row&7 -> conflict-free b128 reads (verified: 0 conflicts R1/R3).
__device__ __forceinline__ int swz(int row, int col) {
  return row * 64 + ((((col >> 3) ^ (row & 7)) << 3) | (col & 7));
}

// ---------------- convert fp32 -> bf16 (vectorized) ----------------
__global__ __launch_bounds__(256)
void k_cvt(const float* __restrict__ src, u16* __restrict__ dst, int n4) {
  int i = blockIdx.x * 256 + threadIdx.x;
  if (i >= n4) return;
  float4 v = ((const float4*)src)[i];
  union { u16 s[4]; uint2 u; } o;
  o.s[0] = f2bf(v.x); o.s[1] = f2bf(v.y); o.s[2] = f2bf(v.z); o.s[3] = f2bf(v.w);
  ((uint2*)dst)[i] = o.u;
}

// ------------- transpose fp32 [R][C] -> bf16 [C][R] (64x64 tiles) -------------
__global__ __launch_bounds__(256)
void k_transpose(const float* __restrict__ src, u16* __restrict__ dst, int R, int Cc) {
  __shared__ u16 t[64 * 66];
  int r0 = blockIdx.y * 64, c0 = blockIdx.x * 64;
  #pragma unroll
  for (int i = 0; i < 16; i++) {
    int e = i * 256 + threadIdx.x;
    int rl = e >> 6, cl = e & 63;
    t[cl * 66 + rl] = f2bf(src[(size_t)(r0 + rl) * Cc + c0 + cl]);
  }
  __syncthreads();
  #pragma unroll
  for (int i = 0; i < 16; i++) {
    int e = i * 256 + threadIdx.x;
    int ro = e >> 6, co = e & 63;
    dst[(size_t)(c0 + ro) * R + r0 + co] = t[ro * 66 + co];
  }
}

// ----- temb projection, stage 1: partial[kt][b][j] = sum_{k in kt} temb[b][k]*Wt[k][j] -----
// K split 32 ways across blocks -> 384 blocks (vs 96 monolithic = 72us latency-bound, R5).
__global__ __launch_bounds__(256)
void k_temb_part(const float* __restrict__ temb, const float* __restrict__ Wt,
                 float* __restrict__ part) {
  const int j = blockIdx.x * 256 + threadIdx.x;   // 0..3071
  const int k0 = blockIdx.y * 32;
  float acc[8];
  #pragma unroll
  for (int b = 0; b < 8; b++) acc[b] = 0.f;
  #pragma unroll 4
  for (int k = k0; k < k0 + 32; k++) {
    float wv = Wt[(size_t)k * 3072 + j];
    #pragma unroll
    for (int b = 0; b < 8; b++) acc[b] += temb[b * 1024 + k] * wv;  // temb: scalar loads
  }
  float* p = part + (size_t)blockIdx.y * 24576 + j;
  #pragma unroll
  for (int b = 0; b < 8; b++) p[b * 3072] = acc[b];
}

// ----- temb projection, stage 2: tcomb[b][j] = sum_kt part + bt[j] + bqkv[j] -----
__global__ __launch_bounds__(256)
void k_temb_red(const float* __restrict__ part, const float* __restrict__ bt,
                const float* __restrict__ bqkv, float* __restrict__ tcomb) {
  const int j = blockIdx.x * 256 + threadIdx.x;   // 0..3071
  const int b = blockIdx.y;
  const float* p = part + b * 3072 + j;
  float a = bt[j] + bqkv[j];
  #pragma unroll
  for (int kt = 0; kt < 32; kt++) a += p[(size_t)kt * 24576];
  tcomb[b * 3072 + j] = a;
}

// ------------- bf16 MFMA GEMM: C[M][Ntot] = A[M][K] @ Bt[N][K]^T -------------
// Block 256M x 128N, 4 waves, wave tile 64M x 128N (reads/MFMA = 0.375).
// Double-buffered LDS, one barrier/iter, prefetch issued after barrier.
// LDS chunk swizzle: 16B chunk cp = c ^ ((row>>1)&3) -> 2-way (free) b128 reads.
template <int MODE>
__global__ __launch_bounds__(256, 2)
void k_gemm(const u16* __restrict__ A, const u16* __restrict__ Bt,
            u16* __restrict__ outb, float* __restrict__ outf,
            const float* __restrict__ bias, int K, int Ntot) {
  __shared__ u16 As[2][8192];   // 256 rows x 32 (K32) u16, swizzled
  __shared__ u16 Bs[2][4096];   // 128 rows x 32
  const int m0 = blockIdx.y * 256;
  const int n0 = blockIdx.x * 128;
  const int lane = threadIdx.x & 63;
  const int w = threadIdx.x >> 6;
  const int l15 = lane & 15;
  const int fo = (((lane >> 4) ^ ((lane >> 1) & 3)) << 3);
  const int srow = lane >> 2;
  const int schunk = (((lane & 3) ^ ((lane >> 3) & 3)) << 3);

  f32x4 acc[4][8];
  #pragma unroll
  for (int i = 0; i < 4; i++)
    #pragma unroll
    for (int j = 0; j < 8; j++) acc[i][j] = (f32x4){0.f, 0.f, 0.f, 0.f};

  const u16* Ag = A + (size_t)(m0 + srow) * K + schunk;
  const u16* Bg = Bt + (size_t)(n0 + srow) * K + schunk;

  const int iters = K >> 5;
  #pragma unroll
  for (int tt = 0; tt < 4; tt++) {
    int t = w * 4 + tt;
    gload16(Ag + (size_t)(16 * t) * K, &As[0][t * 512]);
  }
  #pragma unroll
  for (int tt = 0; tt < 2; tt++) {
    int t = w * 2 + tt;
    gload16(Bg + (size_t)(16 * t) * K, &Bs[0][t * 512]);
  }

  for (int it = 0; it < iters; it++) {
    __syncthreads();
    const int cur = it & 1;
    if (it + 1 < iters) {
      const int nxt = cur ^ 1;
      const int k1 = (it + 1) << 5;
      #pragma unroll
      for (int tt = 0; tt < 4; tt++) {
        int t = w * 4 + tt;
        gload16(Ag + (size_t)(16 * t) * K + k1, &As[nxt][t * 512]);
      }
      #pragma unroll
      for (int tt = 0; tt < 2; tt++) {
        int t = w * 2 + tt;
        gload16(Bg + (size_t)(16 * t) * K + k1, &Bs[nxt][t * 512]);
      }
    }
    bf16x8 af[4], bfr[8];
    #pragma unroll
    for (int i = 0; i < 4; i++)
      af[i] = *(const bf16x8*)&As[cur][(w * 64 + 16 * i + l15) * 32 + fo];
    #pragma unroll
    for (int j = 0; j < 8; j++)
      bfr[j] = *(const bf16x8*)&Bs[cur][(16 * j + l15) * 32 + fo];
    #pragma unroll
    for (int i = 0; i < 4; i++)
      #pragma unroll
      for (int j = 0; j < 8; j++)
        acc[i][j] = mfma16(af[i], bfr[j], acc[i][j]);
  }

  const int rl = (lane >> 4) * 4;
  #pragma unroll
  for (int i = 0; i < 4; i++) {
    #pragma unroll
    for (int j = 0; j < 8; j++) {
      #pragma unroll
      for (int r = 0; r < 4; r++) {
        int grow = m0 + w * 64 + 16 * i + rl + r;
        int gcol = n0 + 16 * j + l15;
        float v = acc[i][j][r];
        if (MODE == 0) {
          int b = grow >> 10;
          v += bias[b * Ntot + gcol];
          outb[(size_t)grow * Ntot + gcol] = f2bf(v);
        } else {
          v += bias[gcol];
          outf[(size_t)grow * Ntot + gcol] = v;
        }
      }
    }
  }
}

// ------- fused per-head RMSNorm + axial RoPE (q,k) + V transpose -------
// Q output pre-scaled by log2(e)/sqrt(64) so attention scores are in the
// exp2 domain directly (softmax(s) == normalized exp2(s*log2e)).
__global__ __launch_bounds__(256)
void k_rrv(const u16* __restrict__ qkv,
           const float* __restrict__ cos_y, const float* __restrict__ sin_y,
           const float* __restrict__ cos_x, const float* __restrict__ sin_x,
           const float* __restrict__ qn_w, const float* __restrict__ kn_w,
           u16* __restrict__ Qo, u16* __restrict__ Ko, u16* __restrict__ VT) {
  __shared__ u16 t[64 * 68];
  const int n0 = blockIdx.x * 64, h = blockIdx.y, b = blockIdx.z;
  const int bh = b * 16 + h;
  const int lane = threadIdx.x & 63, w = threadIdx.x >> 6;
  const int l15 = lane & 15, lg = lane >> 4;
  float4 qw = *(const float4*)(qn_w + l15 * 4);
  float4 kw = *(const float4*)(kn_w + l15 * 4);
  const float sgn = (lane & 4) ? 1.0f : -1.0f;   // rotate partner is d^16 within each 32-half
  const float* ct = (lane & 8) ? cos_x : cos_y;
  const float* st = (lane & 8) ? sin_x : sin_y;
  const float QSCALE = 0.18033688011112042f;     // log2(e)/8

  #pragma unroll
  for (int rr = 0; rr < 4; rr++) {
    int row = n0 + w * 16 + rr * 4 + lg;
    size_t src = (size_t)(b * 1024 + row) * 3072 + h * 64 + l15 * 4;
    uint2 qu = *(const uint2*)(qkv + src);
    uint2 ku = *(const uint2*)(qkv + src + 1024);
    float q[4], k[4];
    q[0] = bf2f((u16)qu.x); q[1] = bf2f((u16)(qu.x >> 16));
    q[2] = bf2f((u16)qu.y); q[3] = bf2f((u16)(qu.y >> 16));
    k[0] = bf2f((u16)ku.x); k[1] = bf2f((u16)(ku.x >> 16));
    k[2] = bf2f((u16)ku.y); k[3] = bf2f((u16)(ku.y >> 16));
    float sq = q[0]*q[0] + q[1]*q[1] + q[2]*q[2] + q[3]*q[3];
    float sk = k[0]*k[0] + k[1]*k[1] + k[2]*k[2] + k[3]*k[3];
    #pragma unroll
    for (int m = 1; m < 16; m <<= 1) {
      sq += __shfl_xor(sq, m);
      sk += __shfl_xor(sk, m);
    }
    float rq = rsqrtf(sq * (1.0f / 64.0f) + 1e-6f);
    float rk = rsqrtf(sk * (1.0f / 64.0f) + 1e-6f);
    float4 cc = *(const float4*)(ct + (size_t)row * 32 + (lane & 7) * 4);
    float4 ss = *(const float4*)(st + (size_t)row * 32 + (lane & 7) * 4);
    float qn[4], kn[4];
    qn[0] = q[0]*rq*qw.x; qn[1] = q[1]*rq*qw.y; qn[2] = q[2]*rq*qw.z; qn[3] = q[3]*rq*qw.w;
    kn[0] = k[0]*rk*kw.x; kn[1] = k[1]*rk*kw.y; kn[2] = k[2]*rk*kw.z; kn[3] = k[3]*rk*kw.w;
    float c[4] = {cc.x, cc.y, cc.z, cc.w};
    float s[4] = {ss.x, ss.y, ss.z, ss.w};
    union { u16 e[4]; uint2 u; } oq, ok;
    #pragma unroll
    for (int j = 0; j < 4; j++) {
      float qp = __shfl_xor(qn[j], 4);   // partner chunk (l15^4) == d^16
      float kp = __shfl_xor(kn[j], 4);
      oq.e[j] = f2bf((qn[j] * c[j] + sgn * qp * s[j]) * QSCALE);
      ok.e[j] = f2bf(kn[j] * c[j] + sgn * kp * s[j]);
    }
    size_t dst = ((size_t)bh * 1024 + row) * 64 + l15 * 4;
    *(uint2*)(Qo + dst) = oq.u;
    *(uint2*)(Ko + dst) = ok.u;
  }

  // V transpose: qkv v-slice [n][d] -> VT [bh][d][n]
  #pragma unroll
  for (int i = 0; i < 4; i++) {
    int e = i * 256 + threadIdx.x;
    int n = e >> 4, dc = e & 15;
    uint2 v = *(const uint2*)(qkv + (size_t)(b * 1024 + n0 + n) * 3072 + 2048 + h * 64 + dc * 4);
    t[(dc * 4 + 0) * 68 + n] = (u16)v.x;
    t[(dc * 4 + 1) * 68 + n] = (u16)(v.x >> 16);
    t[(dc * 4 + 2) * 68 + n] = (u16)v.y;
    t[(dc * 4 + 3) * 68 + n] = (u16)(v.y >> 16);
  }
  __syncthreads();
  #pragma unroll
  for (int i = 0; i < 4; i++) {
    int e = i * 256 + threadIdx.x;
    int d = e >> 4, nc = e & 15;
    const u16* p = &t[d * 68 + nc * 4];
    uint2 o;
    o.x = (uint32_t)p[0] | ((uint32_t)p[1] << 16);
    o.y = (uint32_t)p[2] | ((uint32_t)p[3] << 16);
    *(uint2*)(VT + ((size_t)bh * 64 + d) * 1024 + n0 + nc * 4) = o;
  }
}

// ---------------- flash attention, 128 q-rows/block, dbuf K/V, 1 barrier/iter ----------------
// Fixed-max softmax: scores s2 = (q.k)*log2e/8 are bounded (|s|<=8 by
// Cauchy-Schwarz on RMS-normalized q,k => |s2|<=11.6, exp2<=3e3, l<=3e6 fp32-safe),
// so no running max / alpha rescale; l reduced once in epilogue.
__global__ __launch_bounds__(256, 2)
void k_attn(const u16* __restrict__ Q, const u16* __restrict__ Kb,
            const u16* __restrict__ VT, u16* __restrict__ Ob) {
  __shared__ u16 Ks[2][4096], VTs[2][4096], Ps[4][2048];
  const int lane = threadIdx.x & 63;
  const int w = threadIdx.x >> 6;
  const int bh = blockIdx.x;          // b*16+h : q-tiles of one bh co-locate on an XCD
  const int qt = blockIdx.y;
  const int b = bh >> 4, h = bh & 15;
  const size_t base = (size_t)bh * 65536;
  const int q0 = qt * 128;
  const int scol = ((lane & 7) ^ (lane >> 3)) * 8;  // XOR-swizzled source chunk for staging
  const int lr = lane >> 3;

  // Q fragments in registers (pre-scaled by log2e/8 in k_rrv)
  bf16x8 aq[2][2];
  #pragma unroll
  for (int i = 0; i < 2; i++)
    #pragma unroll
    for (int s = 0; s < 2; s++)
      aq[i][s] = *(const bf16x8*)(Q + base +
          (size_t)(q0 + w * 32 + i * 16 + (lane & 15)) * 64 + s * 32 + (lane >> 4) * 8);

  f32x4 acc_o[2][4];
  float lpar[2][4];
  #pragma unroll
  for (int i = 0; i < 2; i++)
    #pragma unroll
    for (int r = 0; r < 4; r++) {
      acc_o[i][r] = (f32x4){0.f, 0.f, 0.f, 0.f};
      lpar[i][r] = 0.f;
    }

  // stage j-tile 0 into buf 0
  #pragma unroll
  for (int tt = 0; tt < 2; tt++) {
    int t = w * 2 + tt;
    gload16(Kb + base + (size_t)(8 * t + lr) * 64 + scol, &Ks[0][t * 512]);
    gload16(VT + base + (size_t)(8 * t + lr) * 1024 + scol, &VTs[0][t * 512]);
  }

  for (int it = 0; it < 16; it++) {
    __syncthreads();                 // staging of cur complete; all readers of nxt (prev iter) done
    const int cur = it & 1;
    if (it < 15) {                   // prefetch next tile; latency hidden behind this iter's compute
      const int nxt = cur ^ 1;
      const int j1 = (it + 1) * 64;
      #pragma unroll
      for (int tt = 0; tt < 2; tt++) {
        int t = w * 2 + tt;
        gload16(Kb + base + (size_t)(j1 + 8 * t + lr) * 64 + scol, &Ks[nxt][t * 512]);
        gload16(VT + base + (size_t)(8 * t + lr) * 1024 + j1 + scol, &VTs[nxt][t * 512]);
      }
    }
    const u16* K_ = Ks[cur];
    const u16* V_ = VTs[cur];

    // S2 = Qhat K^T (already in exp2 domain)
    f32x4 accs[2][4];
    #pragma unroll
    for (int i = 0; i < 2; i++)
      #pragma unroll
      for (int nt = 0; nt < 4; nt++) accs[i][nt] = (f32x4){0.f, 0.f, 0.f, 0.f};
    #pragma unroll
    for (int s = 0; s < 2; s++) {
      bf16x8 bk[4];
      #pragma unroll
      for (int nt = 0; nt < 4; nt++)
        bk[nt] = *(const bf16x8*)&K_[swz(nt * 16 + (lane & 15), s * 32 + (lane >> 4) * 8)];
      #pragma unroll
      for (int i = 0; i < 2; i++)
        #pragma unroll
        for (int nt = 0; nt < 4; nt++)
          accs[i][nt] = mfma16(aq[i][s], bk[nt], accs[i][nt]);
    }

    // P = exp2(S2); accumulate per-lane l partials; P -> wave-private LDS strip
    #pragma unroll
    for (int i = 0; i < 2; i++) {
      #pragma unroll
      for (int nt = 0; nt < 4; nt++) {
        #pragma unroll
        for (int r = 0; r < 4; r++) {
          float p = __builtin_amdgcn_exp2f(accs[i][nt][r]);
          lpar[i][r] += p;
          Ps[w][swz(i * 16 + (lane >> 4) * 4 + r, nt * 16 + (lane & 15))] = f2bf(p);
        }
      }
    }
    asm volatile("s_waitcnt lgkmcnt(0)" ::: "memory");  // P writes visible to own wave's reads

    // O += P V
    #pragma unroll
    for (int s = 0; s < 2; s++) {
      bf16x8 bv[4];
      #pragma unroll
      for (int dt = 0; dt < 4; dt++)
        bv[dt] = *(const bf16x8*)&V_[swz(dt * 16 + (lane & 15), s * 32 + (lane >> 4) * 8)];
      #pragma unroll
      for (int i = 0; i < 2; i++) {
        bf16x8 ap = *(const bf16x8*)&Ps[w][swz(i * 16 + (lane & 15), s * 32 + (lane >> 4) * 8)];
        #pragma unroll
        for (int dt = 0; dt < 4; dt++)
          acc_o[i][dt] = mfma16(ap, bv[dt], acc_o[i][dt]);
      }
    }
  }

  // epilogue: reduce l over the 16-lane col group (once), O/l -> att [b, n, h*64+d]
  #pragma unroll
  for (int i = 0; i < 2; i++) {
    float inv[4];
    #pragma unroll
    for (int r = 0; r < 4; r++) {
      float l = lpar[i][r];
      #pragma unroll
      for (int m = 1; m < 16; m <<= 1) l += __shfl_xor(l, m);
      inv[r] = 1.0f / l;
    }
    #pragma unroll
    for (int dt = 0; dt < 4; dt++)
      #pragma unroll
      for (int r = 0; r < 4; r++) {
        int row = q0 + w * 32 + i * 16 + (lane >> 4) * 4 + r;
        int col = h * 64 + dt * 16 + (lane & 15);
        Ob[((size_t)b * 1024 + row) * 1024 + col] = f2bf(acc_o[i][dt][r] * inv[r]);
      }
  }
}

// ---------------- launch ----------------
extern "C" void kernel_launch(void* const* d_in, const int* in_sizes, int n_in,
                              void* d_out, int out_size, void* d_ws, size_t ws_size,
                              hipStream_t stream) {
  const float* x     = (const float*)d_in[0];
  const float* temb  = (const float*)d_in[1];
  const float* cos_y = (const float*)d_in[2];
  const float* sin_y = (const float*)d_in[3];
  const float* cos_x = (const float*)d_in[4];
  const float* sin_x = (const float*)d_in[5];
  const float* Wqkv  = (const float*)d_in[6];
  const float* bqkv  = (const float*)d_in[7];
  const float* Wt    = (const float*)d_in[8];
  const float* bt    = (const float*)d_in[9];
  const float* Wp    = (const float*)d_in[10];
  const float* bp    = (const float*)d_in[11];
  const float* qn_w  = (const float*)d_in[12];
  const float* kn_w  = (const float*)d_in[13];
  float* out = (float*)d_out;

  char* ws = (char*)d_ws;
  u16*   x_bf  = (u16*)(ws);                  // 16 MB; reused as att after QKV GEMM
  u16*   WqkvT = (u16*)(ws + 16777216);       // 6 MB
  u16*   WpT   = (u16*)(ws + 23068672);       // 2 MB
  float* tcomb = (float*)(ws + 25165824);     // 96 KB
  u16*   qkv   = (u16*)(ws + 25264128);       // 48 MB
  u16*   Qb    = (u16*)(ws + 75595776);       // 16 MB
  u16*   Kb    = (u16*)(ws + 92372992);       // 16 MB
  u16*   VTb   = (u16*)(ws + 109150208);      // 16 MB
  float* tpart = (float*)(ws + 125927424);    // 3 MB (32*8*3072 fp32)
  u16*   att   = x_bf;

  k_cvt<<<8192, 256, 0, stream>>>(x, x_bf, 8192 * 1024 / 4);
  k_transpose<<<dim3(48, 16), 256, 0, stream>>>(Wqkv, WqkvT, 1024, 3072);
  k_transpose<<<dim3(16, 16), 256, 0, stream>>>(Wp, WpT, 1024, 1024);
  k_temb_part<<<dim3(12, 32), 256, 0, stream>>>(temb, Wt, tpart);
  k_temb_red<<<dim3(12, 8), 256, 0, stream>>>(tpart, bt, bqkv, tcomb);
  k_gemm<0><<<dim3(24, 32), 256, 0, stream>>>(x_bf, WqkvT, qkv, nullptr, tcomb, 1024, 3072);
  k_rrv<<<dim3(16, 16, 8), 256, 0, stream>>>(qkv, cos_y, sin_y, cos_x, sin_x,
                                             qn_w, kn_w, Qb, Kb, VTb);
  k_attn<<<dim3(128, 8), 256, 0, stream>>>(Qb, Kb, VTb, att);
  k_gemm<1><<<dim3(8, 32), 256, 0, stream>>>(att, WpT, nullptr, out, bp, 1024, 1024);
}